// Round 3
// baseline (300.760 us; speedup 1.0000x reference)
//
#include <hip/hip_runtime.h>

// CRF forward (log-partition), SEQ=512, BATCH=1024, TAGS=32, fp32 in/out.
//
// Producer-consumer block: wave 0 = serial MFMA scan (feats only from LDS);
// waves 1-3 = stage chunks of 8 steps into LDS double buffer, converting
// feats -> G = 2^(feat*log2e) in f32.  Relaxed barrier (lgkm drain only) keeps
// staging's global loads in flight across chunk boundaries.
//
// exp2-space recurrence per step (wave 0):
//   D = E*B (2x mfma_f32_16x16x32_bf16), n = D*G, a = mask? n : a, B = pack_bf16(a)
// sigma-layout (R2): lane (q,s): batch s, D slots = its own B slots. Renorm /8 steps.

constexpr int SEQ = 512, BATCH = 1024, TAGS = 32;
constexpr int CHUNK = 8, NCHUNK = SEQ / CHUNK;  // 64 chunks

#define LOG2E 1.4426950408889634f
#define LN2   0.6931471805599453f

typedef __attribute__((ext_vector_type(8))) short short8;
typedef __attribute__((ext_vector_type(4))) float float4v;
union Frag8 { unsigned u[4]; short8 v; };

__device__ __forceinline__ unsigned pk_rn(float x, float y) {  // round-half-up pack
  return __builtin_amdgcn_perm(__float_as_uint(y) + 0x8000u,
                               __float_as_uint(x) + 0x8000u, 0x07060302u);
}
__device__ __forceinline__ unsigned pk_tr(float x, float y) {  // truncate pack (1 op)
  return __builtin_amdgcn_perm(__float_as_uint(y), __float_as_uint(x), 0x07060302u);
}
// barrier WITHOUT vmcnt drain: LDS visibility only; global loads stay in flight
__device__ __forceinline__ void barrier_relaxed() {
  asm volatile("s_waitcnt lgkmcnt(0)\ns_barrier" ::: "memory");
}

extern "C" __global__ void __launch_bounds__(256) crf_fwd3(
    const float* __restrict__ feats, const float* __restrict__ mask,
    const float* __restrict__ trans, float* __restrict__ out) {
  __shared__ float lds_f[2][CHUNK * 512];  // 32 KB: [buf][r*512 + s*32 + swz(h)*16 + swz(w)*4 + p]
  __shared__ float lds_m[2][CHUNK * 16];   // 1 KB
  const int tid = threadIdx.x, wid = tid >> 6, lane = tid & 63;
  const int b0 = blockIdx.x * 16;

  if (wid == 0) {
    // ============ compute wave ============
    const int s = lane & 15, q = lane >> 4;
    const int s3 = s & 3, b2 = (s >> 2) & 1;

    int sig[8];
#pragma unroll
    for (int i = 0; i < 8; ++i) sig[i] = (i < 4) ? (4 * q + i) : (16 + 4 * q + (i - 4));
    Frag8 e0, e1;
#pragma unroll
    for (int p = 0; p < 4; ++p) {
      e0.u[p] = pk_rn(__builtin_amdgcn_exp2f(trans[s * TAGS + sig[2 * p]] * LOG2E),
                      __builtin_amdgcn_exp2f(trans[s * TAGS + sig[2 * p + 1]] * LOG2E));
      e1.u[p] = pk_rn(__builtin_amdgcn_exp2f(trans[(16 + s) * TAGS + sig[2 * p]] * LOG2E),
                      __builtin_amdgcn_exp2f(trans[(16 + s) * TAGS + sig[2 * p + 1]] * LOG2E));
    }
    float ef0[4], ef1[4];
#pragma unroll
    for (int p = 0; p < 4; ++p) {
      ef0[p] = __builtin_amdgcn_exp2f(trans[31 * TAGS + (4 * q + p)] * LOG2E);
      ef1[p] = __builtin_amdgcn_exp2f(trans[31 * TAGS + (16 + 4 * q + p)] * LOG2E);
    }

    float a0[4] = {0.f, 0.f, 0.f, 0.f}, a1[4] = {0.f, 0.f, 0.f, 0.f};
    if (q == 3) a1[2] = 1.0f;            // tag 30
    Frag8 B; B.u[0] = 0u; B.u[1] = 0u; B.u[2] = 0u; B.u[3] = (q == 3) ? 0x3F80u : 0u;
    float c2 = 0.0f;
    const float4v zero = {0.f, 0.f, 0.f, 0.f};

    // lane-constant float-index offsets into a chunk buffer (bank-conflict-free swizzle)
    const int off0 = s * 32 + (0 ^ b2) * 16 + ((q ^ s3) * 4);  // h=0 quad: tags 4q..4q+3
    const int off1 = s * 32 + (1 ^ b2) * 16 + ((q ^ s3) * 4);  // h=1 quad: tags 16+4q..+3

#define STEP_CORE(G0, G1, M)                                                      \
  {                                                                               \
    float4v d0 = __builtin_amdgcn_mfma_f32_16x16x32_bf16(e0.v, B.v, zero, 0, 0, 0); \
    float4v d1 = __builtin_amdgcn_mfma_f32_16x16x32_bf16(e1.v, B.v, zero, 0, 0, 0); \
    float4v n0 = d0 * (G0), n1 = d1 * (G1);                                       \
    bool mm = ((M) != 0.0f);                                                      \
    a0[0] = mm ? n0[0] : a0[0]; a0[1] = mm ? n0[1] : a0[1];                       \
    a0[2] = mm ? n0[2] : a0[2]; a0[3] = mm ? n0[3] : a0[3];                       \
    a1[0] = mm ? n1[0] : a1[0]; a1[1] = mm ? n1[1] : a1[1];                       \
    a1[2] = mm ? n1[2] : a1[2]; a1[3] = mm ? n1[3] : a1[3];                       \
  }
#define PACK_B()                                                                  \
  {                                                                               \
    B.u[0] = pk_tr(a0[0], a0[1]); B.u[1] = pk_tr(a0[2], a0[3]);                   \
    B.u[2] = pk_tr(a1[0], a1[1]); B.u[3] = pk_tr(a1[2], a1[3]);                   \
  }
#define STEP(G0, G1, M) { STEP_CORE(G0, G1, M) PACK_B() }
#define STEP_RENORM(G0, G1, M)                                                    \
  {                                                                               \
    STEP_CORE(G0, G1, M)                                                          \
    float mx = fmaxf(fmaxf(fmaxf(a0[0], a0[1]), fmaxf(a0[2], a0[3])),             \
                     fmaxf(fmaxf(a1[0], a1[1]), fmaxf(a1[2], a1[3])));            \
    mx = fmaxf(mx, __shfl_xor(mx, 16, 64));                                       \
    mx = fmaxf(mx, __shfl_xor(mx, 32, 64));                                       \
    int ex = (int)((__float_as_uint(mx) >> 23) & 0xFFu) - 127;                    \
    float scl = __uint_as_float((unsigned)(127 - ex) << 23);                      \
    a0[0] *= scl; a0[1] *= scl; a0[2] *= scl; a0[3] *= scl;                       \
    a1[0] *= scl; a1[1] *= scl; a1[2] *= scl; a1[3] *= scl;                       \
    c2 += (float)ex;                                                              \
    PACK_B()                                                                      \
  }

    barrier_relaxed();  // chunk 0 staged
    for (int c = 0; c < NCHUNK; ++c) {
      const float* fb = lds_f[c & 1];
      const float* mb = lds_m[c & 1];
      float4v gA0, gA1, gB0, gB1;
      float mA, mB;
#define RD(r, G0, G1, M)                                  \
      {                                                   \
        G0 = *(const float4v*)(fb + (r) * 512 + off0);    \
        G1 = *(const float4v*)(fb + (r) * 512 + off1);    \
        M  = mb[(r) * 16 + s];                            \
      }
      RD(0, gA0, gA1, mA) RD(1, gB0, gB1, mB)
      STEP(gA0, gA1, mA)  RD(2, gA0, gA1, mA)
      STEP(gB0, gB1, mB)  RD(3, gB0, gB1, mB)
      STEP(gA0, gA1, mA)  RD(4, gA0, gA1, mA)
      STEP(gB0, gB1, mB)  RD(5, gB0, gB1, mB)
      STEP(gA0, gA1, mA)  RD(6, gA0, gA1, mA)
      STEP(gB0, gB1, mB)  RD(7, gB0, gB1, mB)
      STEP(gA0, gA1, mA)
      STEP_RENORM(gB0, gB1, mB)   // renorm every 8 steps (growth <= ~2^14.5/step, safe)
      barrier_relaxed();
#undef RD
    }

    // epilogue: out[b] = ln2 * (c2 + log2( sum_j A[j,b] * E_end[j] ))
    float v = a0[0] * ef0[0] + a0[1] * ef0[1] + a0[2] * ef0[2] + a0[3] * ef0[3]
            + a1[0] * ef1[0] + a1[1] * ef1[1] + a1[2] * ef1[2] + a1[3] * ef1[3];
    v += __shfl_xor(v, 16, 64);
    v += __shfl_xor(v, 32, 64);
    float res = LN2 * (c2 + __builtin_amdgcn_logf(v));
    if (q == 0) out[b0 + s] = res;

  } else {
    // ============ staging waves (wid 1..3) ============
    const int base = (wid - 1) * 64 + lane;  // 0..191
    // per-chunk: 1024 float4-quads (8 steps x 16 batches x 8 quads), 128 mask floats
    int goff[6], loff[6];
    bool ok[6];
#pragma unroll
    for (int k = 0; k < 6; ++k) {
      int v = base + k * 192;
      ok[k] = (v < 1024);
      int r = v >> 7, sb = (v >> 3) & 15, h = (v >> 2) & 1, w = v & 3;
      goff[k] = r * (BATCH * TAGS) + (b0 + sb) * 32 + h * 16 + w * 4;
      loff[k] = r * 512 + sb * 32 + ((h ^ ((sb >> 2) & 1)) * 16) + ((w ^ (sb & 3)) * 4);
    }
    const bool okm = (base < 128);
    const int goffm = (base >> 4) * BATCH + b0 + (base & 15);
    const int loffm = (base >> 4) * 16 + (base & 15);

    float4v rg[2][6];  // 2-chunk-deep register pipeline
    float rm[2];

#define LOADC(c, ring)                                                            \
    {                                                                             \
      const float* fsrc = feats + (size_t)(c) * (CHUNK * BATCH * TAGS);           \
      _Pragma("unroll")                                                           \
      for (int k = 0; k < 6; ++k)                                                 \
        if (ok[k]) rg[ring][k] = *(const float4v*)(fsrc + goff[k]);               \
      if (okm) rm[ring] = mask[(size_t)(c) * (CHUNK * BATCH) + goffm];            \
    }
#define WRITEC(c, ring)                                                           \
    {                                                                             \
      float* fdst = lds_f[(c) & 1];                                               \
      _Pragma("unroll")                                                           \
      for (int k = 0; k < 6; ++k)                                                 \
        if (ok[k]) {                                                              \
          float4v g;                                                              \
          g[0] = __builtin_amdgcn_exp2f(rg[ring][k][0] * LOG2E);                  \
          g[1] = __builtin_amdgcn_exp2f(rg[ring][k][1] * LOG2E);                  \
          g[2] = __builtin_amdgcn_exp2f(rg[ring][k][2] * LOG2E);                  \
          g[3] = __builtin_amdgcn_exp2f(rg[ring][k][3] * LOG2E);                  \
          *(float4v*)(fdst + loff[k]) = g;                                        \
        }                                                                         \
      if (okm) lds_m[(c) & 1][loffm] = rm[ring];                                  \
    }

    LOADC(0, 0)
    WRITEC(0, 0)
    LOADC(1, 1)
    LOADC(2, 0)
    barrier_relaxed();
    for (int c = 0; c < NCHUNK; ++c) {
      const int ring = (c + 1) & 1;
      if (c + 1 < NCHUNK) WRITEC(c + 1, ring)
      if (c + 3 < NCHUNK) LOADC(c + 3, ring)
      barrier_relaxed();
    }
  }
}

extern "C" void kernel_launch(void* const* d_in, const int* in_sizes, int n_in,
                              void* d_out, int out_size, void* d_ws, size_t ws_size,
                              hipStream_t stream) {
  const float* feats = (const float*)d_in[0];
  const float* mask  = (const float*)d_in[1];
  const float* trans = (const float*)d_in[2];
  float* out = (float*)d_out;
  dim3 grid(BATCH / 16);  // 64 blocks x (1 compute wave + 3 staging waves)
  dim3 block(256);
  hipLaunchKernelGGL(crf_fwd3, grid, block, 0, stream, feats, mask, trans, out);
}

// Round 4
// 196.439 us; speedup vs baseline: 1.5311x; 1.5311x over previous
//
#include <hip/hip_runtime.h>

// CRF forward (log-partition), SEQ=512, BATCH=1024, TAGS=32, fp32 in/out.
//
// Chunked associative scan, 2 kernels (R4):
//  K1 crf_p1: 8192 waves, one per (batch b, chunk c of 64 steps). Computes the
//    32x32 chunk matrix P_c(b) = prod_t (G_t E) in exp2-space via 4x
//    mfma_f32_16x16x32_bf16 per step with the sigma-layout feedback trick
//    (lane's D outputs ARE its next B-operand slots). Power-of-2 renorm every
//    4 steps -> scalar exponent c2. Epilogue: LDS transpose, store P row-major
//    bf16 (S[j*32+k] = P[j,k]) + c2, coalesced.
//  K2 crf_p2: 512 waves (2 batches each): alpha <- P_c * alpha for c=0..7
//    (swizzle-broadcast matvec), renorm each step, epilogue logsumexp.
//
// Serial chain: 64 (K1, x8192-parallel) + 8 (K2) instead of 512.
// d_ws usage: S = 1024*8 matrices * 1024 bf16 = 16 MB, + 32 KB scales. (<= ws_size assumed)

constexpr int SEQ = 512, BATCH = 1024, TAGS = 32;
constexpr int NC = 8, L = SEQ / NC;  // 8 chunks x 64 steps

#define LOG2E 1.4426950408889634f
#define LN2   0.6931471805599453f

typedef __attribute__((ext_vector_type(8))) short short8;
typedef __attribute__((ext_vector_type(4))) float float4v;
typedef __attribute__((ext_vector_type(4))) unsigned uint4v;
union Frag8 { unsigned u[4]; short8 v; };

__device__ __forceinline__ unsigned pk_rn(float x, float y) {  // round pack, x->low
  return __builtin_amdgcn_perm(__float_as_uint(y) + 0x8000u,
                               __float_as_uint(x) + 0x8000u, 0x07060302u);
}
__device__ __forceinline__ unsigned pk_tr(float x, float y) {  // trunc pack, x->low
  return __builtin_amdgcn_perm(__float_as_uint(y), __float_as_uint(x), 0x07060302u);
}
template <int PAT> __device__ __forceinline__ float swz(float v) {
  return __int_as_float(__builtin_amdgcn_ds_swizzle(__float_as_int(v), PAT));
}

// ================= K1: per-(b,c) chunk matrix product =================
extern "C" __global__ void __launch_bounds__(256) crf_p1(
    const float* __restrict__ feats, const float* __restrict__ mask,
    const float* __restrict__ trans, unsigned short* __restrict__ S,
    float* __restrict__ Sc2) {
  __shared__ float lbuf[4][32][33];
  const int wid = threadIdx.x >> 6, lane = threadIdx.x & 63;
  const int gw = blockIdx.x * 4 + wid;   // 0..8191
  const int b = gw >> 3, c = gw & 7;
  const int s = lane & 15, q = lane >> 4;

  int sig[8];
#pragma unroll
  for (int i = 0; i < 8; ++i) sig[i] = (i < 4) ? (4 * q + i) : (16 + 4 * q + (i - 4));

  Frag8 e0, e1;  // A-operands: E rows (j = s and 16+s), sigma-permuted columns
#pragma unroll
  for (int p = 0; p < 4; ++p) {
    e0.u[p] = pk_rn(__builtin_amdgcn_exp2f(trans[s * TAGS + sig[2 * p]] * LOG2E),
                    __builtin_amdgcn_exp2f(trans[s * TAGS + sig[2 * p + 1]] * LOG2E));
    e1.u[p] = pk_rn(__builtin_amdgcn_exp2f(trans[(16 + s) * TAGS + sig[2 * p]] * LOG2E),
                    __builtin_amdgcn_exp2f(trans[(16 + s) * TAGS + sig[2 * p + 1]] * LOG2E));
  }

  // P (f32 master, D-layout): P_hc[p] = P[h*16+4q+p, c*16+s]. Init identity.
  float4v P00 = {0,0,0,0}, P01 = {0,0,0,0}, P10 = {0,0,0,0}, P11 = {0,0,0,0};
#pragma unroll
  for (int p = 0; p < 4; ++p) {
    float one = (4 * q + p == s) ? 1.f : 0.f;
    P00[p] = one; P11[p] = one;
  }
  Frag8 B0, B1;
  float c2 = 0.f;
  const float4v zerov = {0.f, 0.f, 0.f, 0.f};

#define PACK_B()                                                        \
  { B0.u[0] = pk_tr(P00[0], P00[1]); B0.u[1] = pk_tr(P00[2], P00[3]);   \
    B0.u[2] = pk_tr(P10[0], P10[1]); B0.u[3] = pk_tr(P10[2], P10[3]);   \
    B1.u[0] = pk_tr(P01[0], P01[1]); B1.u[1] = pk_tr(P01[2], P01[3]);   \
    B1.u[2] = pk_tr(P11[0], P11[1]); B1.u[3] = pk_tr(P11[2], P11[3]); }
  PACK_B()

  const size_t tstep = (size_t)BATCH * TAGS;
  const float* f0p = feats + (size_t)(c * L) * tstep + b * TAGS + 4 * q;
  const float* mkp = mask + (size_t)(c * L) * BATCH + b;

  // prefetch ring depth 4 (constant indices only after unroll-4: no scratch)
  float4v fr0[4], fr1[4];
  float mk[4];
#pragma unroll
  for (int d = 0; d < 4; ++d) {
    fr0[d] = *(const float4v*)(f0p + d * tstep);
    fr1[d] = *(const float4v*)(f0p + 16 + d * tstep);
    mk[d]  = mkp[d * BATCH];
  }

#pragma unroll 4
  for (int r = 0; r < L; ++r) {
    const int slot = r & 3;
    const float4v F0r = fr0[slot], F1r = fr1[slot];
    const float mval = mk[slot];
    if (r + 4 < L) {
      fr0[slot] = *(const float4v*)(f0p + (r + 4) * tstep);
      fr1[slot] = *(const float4v*)(f0p + 16 + (r + 4) * tstep);
      mk[slot]  = mkp[(r + 4) * BATCH];
    }
    if (__ballot(mval != 0.0f) != 0ull) {   // wave-uniform (mask is per (t,b))
      float4v D00 = __builtin_amdgcn_mfma_f32_16x16x32_bf16(e0.v, B0.v, zerov, 0, 0, 0);
      float4v D01 = __builtin_amdgcn_mfma_f32_16x16x32_bf16(e0.v, B1.v, zerov, 0, 0, 0);
      float4v D10 = __builtin_amdgcn_mfma_f32_16x16x32_bf16(e1.v, B0.v, zerov, 0, 0, 0);
      float4v D11 = __builtin_amdgcn_mfma_f32_16x16x32_bf16(e1.v, B1.v, zerov, 0, 0, 0);
      float4v F0, F1;
#pragma unroll
      for (int p = 0; p < 4; ++p) {
        F0[p] = __builtin_amdgcn_exp2f(F0r[p] * LOG2E);
        F1[p] = __builtin_amdgcn_exp2f(F1r[p] * LOG2E);
      }
      P00 = D00 * F0; P01 = D01 * F0;   // row-scale: rows h0 by F0, h1 by F1
      P10 = D10 * F1; P11 = D11 * F1;
    }
    if (slot == 3) {  // unconditional renorm (robust even under masked steps)
      float mx = fmaxf(fmaxf(fmaxf(P00[0], P00[1]), fmaxf(P00[2], P00[3])),
                 fmaxf(fmaxf(fmaxf(P01[0], P01[1]), fmaxf(P01[2], P01[3])),
                 fmaxf(fmaxf(fmaxf(P10[0], P10[1]), fmaxf(P10[2], P10[3])),
                       fmaxf(fmaxf(P11[0], P11[1]), fmaxf(P11[2], P11[3])))));
      mx = fmaxf(mx, __shfl_xor(mx, 1, 64));
      mx = fmaxf(mx, __shfl_xor(mx, 2, 64));
      mx = fmaxf(mx, __shfl_xor(mx, 4, 64));
      mx = fmaxf(mx, __shfl_xor(mx, 8, 64));
      mx = fmaxf(mx, __shfl_xor(mx, 16, 64));
      mx = fmaxf(mx, __shfl_xor(mx, 32, 64));
      int ex = (int)((__float_as_uint(mx) >> 23) & 0xFFu) - 127;
      float scl = __uint_as_float((unsigned)(127 - ex) << 23);  // exact 2^-ex
      P00 *= scl; P01 *= scl; P10 *= scl; P11 *= scl;
      c2 += (float)ex;
    }
    PACK_B()
  }

  // ---- epilogue: LDS transpose -> row-major bf16 store S[j*32+k]=P[j,k] ----
#pragma unroll
  for (int p = 0; p < 4; ++p) {
    lbuf[wid][4 * q + p][s]           = P00[p];
    lbuf[wid][4 * q + p][16 + s]      = P01[p];
    lbuf[wid][16 + 4 * q + p][s]      = P10[p];
    lbuf[wid][16 + 4 * q + p][16 + s] = P11[p];
  }
  // same-wave LDS RAW: compiler inserts lgkmcnt wait
  const int j = lane >> 1, half = lane & 1;
  unsigned dw[8];
#pragma unroll
  for (int w = 0; w < 8; ++w)
    dw[w] = pk_tr(lbuf[wid][j][half * 16 + 2 * w], lbuf[wid][j][half * 16 + 2 * w + 1]);
  uint4v st0 = {dw[0], dw[1], dw[2], dw[3]}, st1 = {dw[4], dw[5], dw[6], dw[7]};
  unsigned short* Sp = S + ((size_t)gw << 10) + j * 32 + half * 16;
  *(uint4v*)(Sp)     = st0;
  *(uint4v*)(Sp + 8) = st1;
  if (lane == 0) Sc2[gw] = c2;
}

// ================= K2: serial chunk combine + epilogue =================
extern "C" __global__ void __launch_bounds__(64) crf_p2(
    const unsigned short* __restrict__ S, const float* __restrict__ Sc2,
    const float* __restrict__ trans, float* __restrict__ out) {
  const int lane = threadIdx.x, j = lane & 31;
  const int b = blockIdx.x * 2 + (lane >> 5);
  float alpha = (j == 30) ? 1.f : 0.f;  // alpha0 = delta(START=30), exp2-space
  float c2 = 0.f;

  const uint4v* rp = (const uint4v*)(S + ((size_t)(b * NC) << 10) + j * 32);
  uint4v ra = rp[0], rb = rp[1], rc = rp[2], rd = rp[3];  // row j of P_0, k=0..31
  float pc = Sc2[b * NC];

#define ACC2(dwv, k0)                                                          \
  { unsigned d_ = (dwv);                                                       \
    acc0 = fmaf(swz<((k0) << 5)>(alpha), __uint_as_float(d_ << 16), acc0);     \
    acc1 = fmaf(swz<(((k0) + 1) << 5)>(alpha), __uint_as_float(d_ & 0xFFFF0000u), acc1); }

#pragma unroll
  for (int c = 0; c < NC; ++c) {
    uint4v ca = ra, cb = rb, cc = rc, cd = rd;
    float cpc = pc;
    if (c + 1 < NC) {  // prefetch next chunk's row while computing
      const uint4v* np = rp + (c + 1) * 128;
      ra = np[0]; rb = np[1]; rc = np[2]; rd = np[3];
      pc = Sc2[b * NC + c + 1];
    }
    float acc0 = 0.f, acc1 = 0.f;
    ACC2(ca[0], 0)  ACC2(ca[1], 2)  ACC2(ca[2], 4)  ACC2(ca[3], 6)
    ACC2(cb[0], 8)  ACC2(cb[1], 10) ACC2(cb[2], 12) ACC2(cb[3], 14)
    ACC2(cc[0], 16) ACC2(cc[1], 18) ACC2(cc[2], 20) ACC2(cc[3], 22)
    ACC2(cd[0], 24) ACC2(cd[1], 26) ACC2(cd[2], 28) ACC2(cd[3], 30)
    float an = acc0 + acc1;
    // renorm within the 32-lane batch group (exact power of 2)
    float mx = an;
    mx = fmaxf(mx, swz<0x041f>(mx));
    mx = fmaxf(mx, swz<0x081f>(mx));
    mx = fmaxf(mx, swz<0x101f>(mx));
    mx = fmaxf(mx, swz<0x201f>(mx));
    mx = fmaxf(mx, swz<0x401f>(mx));
    int ex = (int)((__float_as_uint(mx) >> 23) & 0xFFu) - 127;
    float scl = __uint_as_float((unsigned)(127 - ex) << 23);
    alpha = an * scl;
    c2 += cpc + (float)ex;
  }

  // out[b] = ln2 * (c2 + log2( sum_j alpha[j] * 2^(trans2[END=31][j]) ))
  float v = alpha * __builtin_amdgcn_exp2f(trans[31 * TAGS + j] * LOG2E);
  v += swz<0x041f>(v); v += swz<0x081f>(v); v += swz<0x101f>(v);
  v += swz<0x201f>(v); v += swz<0x401f>(v);
  float res = LN2 * (c2 + __builtin_amdgcn_logf(v));
  if (j == 0) out[b] = res;
}

extern "C" void kernel_launch(void* const* d_in, const int* in_sizes, int n_in,
                              void* d_out, int out_size, void* d_ws, size_t ws_size,
                              hipStream_t stream) {
  const float* feats = (const float*)d_in[0];
  const float* mask  = (const float*)d_in[1];
  const float* trans = (const float*)d_in[2];
  float* out = (float*)d_out;
  unsigned short* S = (unsigned short*)d_ws;                       // 16 MB
  float* Sc2 = (float*)((char*)d_ws + (size_t)BATCH * NC * TAGS * TAGS * 2);  // +32 KB
  hipLaunchKernelGGL(crf_p1, dim3(BATCH * NC / 4), dim3(256), 0, stream,
                     feats, mask, trans, S, Sc2);
  hipLaunchKernelGGL(crf_p2, dim3(BATCH / 2), dim3(64), 0, stream,
                     S, Sc2, trans, out);
}

// Round 5
// 179.902 us; speedup vs baseline: 1.6718x; 1.0919x over previous
//
#include <hip/hip_runtime.h>

// CRF forward (log-partition), SEQ=512, BATCH=1024, TAGS=32, fp32 in/out.
//
// R5 = R4 chunked associative scan + (a) pass p0 precomputing G=bf16(2^feat2)
// in K1's per-lane packed layout (kills the 16x-redundant per-step exp2),
// (b) scalar (SMEM) mask path, (c) renorm every 8 steps, (d) pk-friendly muls.
//
//  p0 crf_p0: G[t,b] = 64 B: 4 q-blocks, each 8 bf16 = rows {4q..4q+3,16+4q..+3}.
//  K1 crf_p1: wave per (b, chunk of 64): P_c = prod_t diag(F_t)E via 4x
//     mfma_f32_16x16x32_bf16 with sigma-layout feedback (lane's D outputs ARE
//     its next B slots). Renorm by exact 2^-ex every 8 steps -> c2.
//  K2 crf_p2: 8 serial chunk matvecs per batch + logsumexp epilogue (as R4).
//
// ws: G 32 MB | S 16 MB | Sc2 32 KB  (~50.4 MB total)

constexpr int SEQ = 512, BATCH = 1024, TAGS = 32;
constexpr int NC = 8, L = SEQ / NC;  // 8 chunks x 64 steps

#define LOG2E 1.4426950408889634f
#define LN2   0.6931471805599453f

typedef __attribute__((ext_vector_type(8))) short short8;
typedef __attribute__((ext_vector_type(4))) float float4v;
typedef __attribute__((ext_vector_type(4))) unsigned uint4v;
union Frag8 { unsigned u[4]; short8 v; };

__device__ __forceinline__ unsigned pk_rn(float x, float y) {  // round pack, x->low
  return __builtin_amdgcn_perm(__float_as_uint(y) + 0x8000u,
                               __float_as_uint(x) + 0x8000u, 0x07060302u);
}
__device__ __forceinline__ unsigned pk_tr(float x, float y) {  // trunc pack, x->low
  return __builtin_amdgcn_perm(__float_as_uint(y), __float_as_uint(x), 0x07060302u);
}
template <int PAT> __device__ __forceinline__ float swz(float v) {
  return __int_as_float(__builtin_amdgcn_ds_swizzle(__float_as_int(v), PAT));
}

// ================= p0: G = bf16(2^(feat*log2e)), packed per (t,b,q) =================
extern "C" __global__ void __launch_bounds__(256) crf_p0(
    const float* __restrict__ feats, unsigned* __restrict__ G) {
  const int gid = blockIdx.x * 256 + threadIdx.x;  // 0..2097151
  const int tb = gid >> 2, sub = gid & 3;
  const float4v fA = *(const float4v*)(feats + (size_t)tb * 32 + 4 * sub);
  const float4v fB = *(const float4v*)(feats + (size_t)tb * 32 + 16 + 4 * sub);
  uint4v o;
  o[0] = pk_rn(__builtin_amdgcn_exp2f(fA[0] * LOG2E), __builtin_amdgcn_exp2f(fA[1] * LOG2E));
  o[1] = pk_rn(__builtin_amdgcn_exp2f(fA[2] * LOG2E), __builtin_amdgcn_exp2f(fA[3] * LOG2E));
  o[2] = pk_rn(__builtin_amdgcn_exp2f(fB[0] * LOG2E), __builtin_amdgcn_exp2f(fB[1] * LOG2E));
  o[3] = pk_rn(__builtin_amdgcn_exp2f(fB[2] * LOG2E), __builtin_amdgcn_exp2f(fB[3] * LOG2E));
  *(uint4v*)(G + (size_t)tb * 16 + sub * 4) = o;
}

// ================= K1: per-(b,c) chunk matrix product =================
extern "C" __global__ void __launch_bounds__(256) crf_p1(
    const unsigned* __restrict__ G, const float* __restrict__ mask,
    const float* __restrict__ trans, unsigned short* __restrict__ S,
    float* __restrict__ Sc2) {
  __shared__ float lbuf[4][32][33];
  const int wid_u = __builtin_amdgcn_readfirstlane((int)(threadIdx.x >> 6));
  const int lane = threadIdx.x & 63;
  const int gw = blockIdx.x * 4 + wid_u;  // 0..8191 (uniform per wave)
  const int b = gw >> 3, c = gw & 7;
  const int s = lane & 15, q = lane >> 4;

  int sig[8];
#pragma unroll
  for (int i = 0; i < 8; ++i) sig[i] = (i < 4) ? (4 * q + i) : (16 + 4 * q + (i - 4));

  Frag8 e0, e1;  // A-operands: E rows (j = s and 16+s), sigma-permuted columns
#pragma unroll
  for (int p = 0; p < 4; ++p) {
    e0.u[p] = pk_rn(__builtin_amdgcn_exp2f(trans[s * TAGS + sig[2 * p]] * LOG2E),
                    __builtin_amdgcn_exp2f(trans[s * TAGS + sig[2 * p + 1]] * LOG2E));
    e1.u[p] = pk_rn(__builtin_amdgcn_exp2f(trans[(16 + s) * TAGS + sig[2 * p]] * LOG2E),
                    __builtin_amdgcn_exp2f(trans[(16 + s) * TAGS + sig[2 * p + 1]] * LOG2E));
  }

  // P (f32, D-layout): P_hc[p] = P[h*16+4q+p, c*16+s]. Init identity.
  float4v P00 = {0,0,0,0}, P01 = {0,0,0,0}, P10 = {0,0,0,0}, P11 = {0,0,0,0};
#pragma unroll
  for (int p = 0; p < 4; ++p) {
    float one = (4 * q + p == s) ? 1.f : 0.f;
    P00[p] = one; P11[p] = one;
  }
  Frag8 B0, B1;
  float c2 = 0.f;
  const float4v zerov = {0.f, 0.f, 0.f, 0.f};

#define PACK_B()                                                        \
  { B0.u[0] = pk_tr(P00[0], P00[1]); B0.u[1] = pk_tr(P00[2], P00[3]);   \
    B0.u[2] = pk_tr(P10[0], P10[1]); B0.u[3] = pk_tr(P10[2], P10[3]);   \
    B1.u[0] = pk_tr(P01[0], P01[1]); B1.u[1] = pk_tr(P01[2], P01[3]);   \
    B1.u[2] = pk_tr(P11[0], P11[1]); B1.u[3] = pk_tr(P11[2], P11[3]); }
  PACK_B()

  // G stream: lane reads 16 B/step at gbase + t*65536 (wave-step stride)
  const char* gbase = (const char*)G + ((size_t)(c * L) * 1024 + b) * 64 + q * 16;
  // mask: fully scalar path (uniform address -> s_load, bits-nonzero test)
  const unsigned* mki = (const unsigned*)mask + (size_t)(c * L) * BATCH + b;

  uint4v fr[4];  // prefetch ring depth 4 (const indices after unroll-8)
#pragma unroll
  for (int d = 0; d < 4; ++d) fr[d] = *(const uint4v*)(gbase + d * 65536);

#pragma unroll 8
  for (int r = 0; r < L; ++r) {
    const int slot = r & 3;
    const uint4v g = fr[slot];
    if (r + 4 < L) fr[slot] = *(const uint4v*)(gbase + (r + 4) * 65536);

    if (mki[r * BATCH] != 0u) {  // scalar branch; mask is exactly 0.0f/1.0f
      float4v D00 = __builtin_amdgcn_mfma_f32_16x16x32_bf16(e0.v, B0.v, zerov, 0, 0, 0);
      float4v D01 = __builtin_amdgcn_mfma_f32_16x16x32_bf16(e0.v, B1.v, zerov, 0, 0, 0);
      float4v D10 = __builtin_amdgcn_mfma_f32_16x16x32_bf16(e1.v, B0.v, zerov, 0, 0, 0);
      float4v D11 = __builtin_amdgcn_mfma_f32_16x16x32_bf16(e1.v, B1.v, zerov, 0, 0, 0);
      float4v F0, F1;  // unpack bf16->f32: shift/mask only
      F0[0] = __uint_as_float(g[0] << 16); F0[1] = __uint_as_float(g[0] & 0xFFFF0000u);
      F0[2] = __uint_as_float(g[1] << 16); F0[3] = __uint_as_float(g[1] & 0xFFFF0000u);
      F1[0] = __uint_as_float(g[2] << 16); F1[1] = __uint_as_float(g[2] & 0xFFFF0000u);
      F1[2] = __uint_as_float(g[3] << 16); F1[3] = __uint_as_float(g[3] & 0xFFFF0000u);
      P00 = D00 * F0; P01 = D01 * F0;  // rows h0 scaled by F0, h1 by F1
      P10 = D10 * F1; P11 = D11 * F1;
      PACK_B()
    }

    if ((r & 7) == 7) {  // renorm every 8 steps (growth <= 2^13.7/step, 2^111 < 2^127)
      float4v m4 = __builtin_elementwise_max(__builtin_elementwise_max(P00, P01),
                                             __builtin_elementwise_max(P10, P11));
      float mx = fmaxf(fmaxf(m4[0], m4[1]), fmaxf(m4[2], m4[3]));
      mx = fmaxf(mx, __shfl_xor(mx, 1, 64));
      mx = fmaxf(mx, __shfl_xor(mx, 2, 64));
      mx = fmaxf(mx, __shfl_xor(mx, 4, 64));
      mx = fmaxf(mx, __shfl_xor(mx, 8, 64));
      mx = fmaxf(mx, __shfl_xor(mx, 16, 64));
      mx = fmaxf(mx, __shfl_xor(mx, 32, 64));
      int ex = (int)((__float_as_uint(mx) >> 23) & 0xFFu) - 127;
      float scl = __uint_as_float((unsigned)(127 - ex) << 23);  // exact 2^-ex
      P00 *= scl; P01 *= scl; P10 *= scl; P11 *= scl;
      c2 += (float)ex;
      PACK_B()
    }
  }

  // ---- epilogue: LDS transpose -> row-major bf16 store S[j*32+k]=P[j,k] ----
#pragma unroll
  for (int p = 0; p < 4; ++p) {
    lbuf[wid_u][4 * q + p][s]           = P00[p];
    lbuf[wid_u][4 * q + p][16 + s]      = P01[p];
    lbuf[wid_u][16 + 4 * q + p][s]      = P10[p];
    lbuf[wid_u][16 + 4 * q + p][16 + s] = P11[p];
  }
  const int j = lane >> 1, half = lane & 1;
  unsigned dw[8];
#pragma unroll
  for (int w = 0; w < 8; ++w)
    dw[w] = pk_tr(lbuf[wid_u][j][half * 16 + 2 * w], lbuf[wid_u][j][half * 16 + 2 * w + 1]);
  uint4v st0 = {dw[0], dw[1], dw[2], dw[3]}, st1 = {dw[4], dw[5], dw[6], dw[7]};
  unsigned short* Sp = S + ((size_t)gw << 10) + j * 32 + half * 16;
  *(uint4v*)(Sp)     = st0;
  *(uint4v*)(Sp + 8) = st1;
  if (lane == 0) Sc2[gw] = c2;
}

// ================= K2: serial chunk combine + epilogue (as R4) =================
extern "C" __global__ void __launch_bounds__(64) crf_p2(
    const unsigned short* __restrict__ S, const float* __restrict__ Sc2,
    const float* __restrict__ trans, float* __restrict__ out) {
  const int lane = threadIdx.x, j = lane & 31;
  const int b = blockIdx.x * 2 + (lane >> 5);
  float alpha = (j == 30) ? 1.f : 0.f;  // alpha0 = delta(START=30), exp2-space
  float c2 = 0.f;

  const uint4v* rp = (const uint4v*)(S + ((size_t)(b * NC) << 10) + j * 32);
  uint4v ra = rp[0], rb = rp[1], rc = rp[2], rd = rp[3];
  float pc = Sc2[b * NC];

#define ACC2(dwv, k0)                                                          \
  { unsigned d_ = (dwv);                                                       \
    acc0 = fmaf(swz<((k0) << 5)>(alpha), __uint_as_float(d_ << 16), acc0);     \
    acc1 = fmaf(swz<(((k0) + 1) << 5)>(alpha), __uint_as_float(d_ & 0xFFFF0000u), acc1); }

#pragma unroll
  for (int c = 0; c < NC; ++c) {
    uint4v ca = ra, cb = rb, cc = rc, cd = rd;
    float cpc = pc;
    if (c + 1 < NC) {
      const uint4v* np = rp + (c + 1) * 128;
      ra = np[0]; rb = np[1]; rc = np[2]; rd = np[3];
      pc = Sc2[b * NC + c + 1];
    }
    float acc0 = 0.f, acc1 = 0.f;
    ACC2(ca[0], 0)  ACC2(ca[1], 2)  ACC2(ca[2], 4)  ACC2(ca[3], 6)
    ACC2(cb[0], 8)  ACC2(cb[1], 10) ACC2(cb[2], 12) ACC2(cb[3], 14)
    ACC2(cc[0], 16) ACC2(cc[1], 18) ACC2(cc[2], 20) ACC2(cc[3], 22)
    ACC2(cd[0], 24) ACC2(cd[1], 26) ACC2(cd[2], 28) ACC2(cd[3], 30)
    float an = acc0 + acc1;
    float mx = an;
    mx = fmaxf(mx, swz<0x041f>(mx));
    mx = fmaxf(mx, swz<0x081f>(mx));
    mx = fmaxf(mx, swz<0x101f>(mx));
    mx = fmaxf(mx, swz<0x201f>(mx));
    mx = fmaxf(mx, swz<0x401f>(mx));
    int ex = (int)((__float_as_uint(mx) >> 23) & 0xFFu) - 127;
    float scl = __uint_as_float((unsigned)(127 - ex) << 23);
    alpha = an * scl;
    c2 += cpc + (float)ex;
  }

  float v = alpha * __builtin_amdgcn_exp2f(trans[31 * TAGS + j] * LOG2E);
  v += swz<0x041f>(v); v += swz<0x081f>(v); v += swz<0x101f>(v);
  v += swz<0x201f>(v); v += swz<0x401f>(v);
  float res = LN2 * (c2 + __builtin_amdgcn_logf(v));
  if (j == 0) out[b] = res;
}

extern "C" void kernel_launch(void* const* d_in, const int* in_sizes, int n_in,
                              void* d_out, int out_size, void* d_ws, size_t ws_size,
                              hipStream_t stream) {
  const float* feats = (const float*)d_in[0];
  const float* mask  = (const float*)d_in[1];
  const float* trans = (const float*)d_in[2];
  float* out = (float*)d_out;
  unsigned* Gbuf = (unsigned*)d_ws;                                   // 32 MB
  unsigned short* S = (unsigned short*)((char*)d_ws + 33554432);      // 16 MB
  float* Sc2 = (float*)((char*)d_ws + 33554432 + 16777216);           // 32 KB
  hipLaunchKernelGGL(crf_p0, dim3(8192), dim3(256), 0, stream, feats, Gbuf);
  hipLaunchKernelGGL(crf_p1, dim3(BATCH * NC / 4), dim3(256), 0, stream,
                     Gbuf, mask, trans, S, Sc2);
  hipLaunchKernelGGL(crf_p2, dim3(BATCH / 2), dim3(64), 0, stream,
                     S, Sc2, trans, out);
}

// Round 6
// 156.550 us; speedup vs baseline: 1.9212x; 1.1492x over previous
//
#include <hip/hip_runtime.h>

// CRF forward (log-partition), SEQ=512, BATCH=1024, TAGS=32, fp32 in/out.
//
// R6: fuse R5's p0 (G = bf16(2^feat2)) INTO p1 via per-wave LDS staging.
//  K1 crf_p1: wave per (batch b, chunk c of 64 steps).
//    Stage: lane t loads its feats row (128B contiguous), 32 distinct exp2,
//    pack bf16 q-block order, 4x ds_write_b128 -> per-wave 4KB LDS chunk.
//    Loop: ds_read_b128 (immediate offsets, 16-way broadcast, 0 conflicts,
//    2-deep prefetch) + 4x mfma_f32_16x16x32_bf16 sigma-feedback (lane's D
//    outputs ARE its next B slots) + row-scale + renorm-by-2^ex every 8.
//  K2 crf_p2: 8 serial chunk matvecs per batch (swizzle broadcast) + lse.
//
// ws: S 16 MB | Sc2 32 KB.

constexpr int SEQ = 512, BATCH = 1024, TAGS = 32;
constexpr int NC = 8, L = SEQ / NC;  // 8 chunks x 64 steps

#define LOG2E 1.4426950408889634f
#define LN2   0.6931471805599453f

typedef __attribute__((ext_vector_type(8))) short short8;
typedef __attribute__((ext_vector_type(4))) float float4v;
typedef __attribute__((ext_vector_type(4))) unsigned uint4v;
union Frag8 { unsigned u[4]; short8 v; };

__device__ __forceinline__ unsigned pk_rn(float x, float y) {  // bf16 pack, x->low
  return __builtin_amdgcn_perm(__float_as_uint(y) + 0x8000u,
                               __float_as_uint(x) + 0x8000u, 0x07060302u);
}
__device__ __forceinline__ unsigned pk_tr(float x, float y) {  // trunc pack, x->low
  return __builtin_amdgcn_perm(__float_as_uint(y), __float_as_uint(x), 0x07060302u);
}
template <int PAT> __device__ __forceinline__ float swz(float v) {
  return __int_as_float(__builtin_amdgcn_ds_swizzle(__float_as_int(v), PAT));
}

// ================= K1: fused stage + per-(b,c) chunk matrix product =================
extern "C" __global__ void __launch_bounds__(256) crf_p1(
    const float* __restrict__ feats, const float* __restrict__ mask,
    const float* __restrict__ trans, unsigned short* __restrict__ S,
    float* __restrict__ Sc2) {
  // per-wave region: 1088 dwords = staging G (1024: row t at t*16 dwords) and,
  // later, the 32x33 f32 epilogue transpose (1056) — lifetimes disjoint.
  __shared__ unsigned gshare[4][1088];
  const int wid_u = __builtin_amdgcn_readfirstlane((int)(threadIdx.x >> 6));
  const int lane = threadIdx.x & 63;
  const int gw = blockIdx.x * 4 + wid_u;  // 0..8191 (uniform per wave)
  const int b = gw >> 3, c = gw & 7;
  const int s = lane & 15, q = lane >> 4;
  unsigned* Wg = &gshare[wid_u][0];

  // ---- stage: lane t = lane handles row t of this chunk ----
  {
    const float* fro = feats + ((size_t)(c * L + lane) * BATCH + b) * TAGS;
    float4v fa0 = *(const float4v*)(fro);
    float4v fa1 = *(const float4v*)(fro + 4);
    float4v fa2 = *(const float4v*)(fro + 8);
    float4v fa3 = *(const float4v*)(fro + 12);
    float4v fb0 = *(const float4v*)(fro + 16);
    float4v fb1 = *(const float4v*)(fro + 20);
    float4v fb2 = *(const float4v*)(fro + 24);
    float4v fb3 = *(const float4v*)(fro + 28);
    float ea[16], eb[16];
#pragma unroll
    for (int i = 0; i < 4; ++i) {
      ea[4 * 0 + i] = __builtin_amdgcn_exp2f(fa0[i] * LOG2E);
      ea[4 * 1 + i] = __builtin_amdgcn_exp2f(fa1[i] * LOG2E);
      ea[4 * 2 + i] = __builtin_amdgcn_exp2f(fa2[i] * LOG2E);
      ea[4 * 3 + i] = __builtin_amdgcn_exp2f(fa3[i] * LOG2E);
      eb[4 * 0 + i] = __builtin_amdgcn_exp2f(fb0[i] * LOG2E);
      eb[4 * 1 + i] = __builtin_amdgcn_exp2f(fb1[i] * LOG2E);
      eb[4 * 2 + i] = __builtin_amdgcn_exp2f(fb2[i] * LOG2E);
      eb[4 * 3 + i] = __builtin_amdgcn_exp2f(fb3[i] * LOG2E);
    }
    // row layout: 4 q-blocks of 16B; block q = pairs (4q,4q+1)(4q+2,4q+3)(16+4q,..)(16+4q+2,..)
#pragma unroll
    for (int qq = 0; qq < 4; ++qq) {
      uint4v dwv;
      dwv[0] = pk_rn(ea[4 * qq + 0], ea[4 * qq + 1]);
      dwv[1] = pk_rn(ea[4 * qq + 2], ea[4 * qq + 3]);
      dwv[2] = pk_rn(eb[4 * qq + 0], eb[4 * qq + 1]);
      dwv[3] = pk_rn(eb[4 * qq + 2], eb[4 * qq + 3]);
      *(uint4v*)(Wg + lane * 16 + qq * 4) = dwv;
    }
  }

  // ---- constants: sigma-permuted E fragments ----
  int sig[8];
#pragma unroll
  for (int i = 0; i < 8; ++i) sig[i] = (i < 4) ? (4 * q + i) : (16 + 4 * q + (i - 4));
  Frag8 e0, e1;
#pragma unroll
  for (int p = 0; p < 4; ++p) {
    e0.u[p] = pk_rn(__builtin_amdgcn_exp2f(trans[s * TAGS + sig[2 * p]] * LOG2E),
                    __builtin_amdgcn_exp2f(trans[s * TAGS + sig[2 * p + 1]] * LOG2E));
    e1.u[p] = pk_rn(__builtin_amdgcn_exp2f(trans[(16 + s) * TAGS + sig[2 * p]] * LOG2E),
                    __builtin_amdgcn_exp2f(trans[(16 + s) * TAGS + sig[2 * p + 1]] * LOG2E));
  }

  // P (f32, D-layout): P_hc[p] = P[h*16+4q+p, c*16+s]. Init identity.
  float4v P00 = {0,0,0,0}, P01 = {0,0,0,0}, P10 = {0,0,0,0}, P11 = {0,0,0,0};
#pragma unroll
  for (int p = 0; p < 4; ++p) {
    float one = (4 * q + p == s) ? 1.f : 0.f;
    P00[p] = one; P11[p] = one;
  }
  Frag8 B0, B1;
  float c2 = 0.f;
  const float4v zerov = {0.f, 0.f, 0.f, 0.f};

#define PACK_B()                                                        \
  { B0.u[0] = pk_tr(P00[0], P00[1]); B0.u[1] = pk_tr(P00[2], P00[3]);   \
    B0.u[2] = pk_tr(P10[0], P10[1]); B0.u[3] = pk_tr(P10[2], P10[3]);   \
    B1.u[0] = pk_tr(P01[0], P01[1]); B1.u[1] = pk_tr(P01[2], P01[3]);   \
    B1.u[2] = pk_tr(P11[0], P11[1]); B1.u[3] = pk_tr(P11[2], P11[3]); }
  PACK_B()

  // mask: fully scalar path (wave-uniform address -> s_load + s_cmp)
  const unsigned* mki = (const unsigned*)mask + (size_t)(c * L) * BATCH + b;

  // G reads: per-wave LDS, immediate offsets, 16-way broadcast across s
  const uint4v* Wq = (const uint4v*)(Wg + q * 4);  // element t*4 = row t's q-block
#define RDG(t) (Wq[(t) * 4])

  uint4v g0 = RDG(0), g1 = RDG(1);  // 2-deep prefetch (reg-named)

#pragma unroll 8
  for (int r = 0; r < L; ++r) {
    const uint4v g = (r & 1) ? g1 : g0;
    if (r + 2 < L) { if (r & 1) g1 = RDG(r + 2); else g0 = RDG(r + 2); }

    if (mki[r * BATCH] != 0u) {  // mask is exactly 0.0f/1.0f
      float4v D00 = __builtin_amdgcn_mfma_f32_16x16x32_bf16(e0.v, B0.v, zerov, 0, 0, 0);
      float4v D01 = __builtin_amdgcn_mfma_f32_16x16x32_bf16(e0.v, B1.v, zerov, 0, 0, 0);
      float4v D10 = __builtin_amdgcn_mfma_f32_16x16x32_bf16(e1.v, B0.v, zerov, 0, 0, 0);
      float4v D11 = __builtin_amdgcn_mfma_f32_16x16x32_bf16(e1.v, B1.v, zerov, 0, 0, 0);
      float4v F0, F1;  // unpack bf16->f32: shift/mask only
      F0[0] = __uint_as_float(g[0] << 16); F0[1] = __uint_as_float(g[0] & 0xFFFF0000u);
      F0[2] = __uint_as_float(g[1] << 16); F0[3] = __uint_as_float(g[1] & 0xFFFF0000u);
      F1[0] = __uint_as_float(g[2] << 16); F1[1] = __uint_as_float(g[2] & 0xFFFF0000u);
      F1[2] = __uint_as_float(g[3] << 16); F1[3] = __uint_as_float(g[3] & 0xFFFF0000u);
      P00 = D00 * F0; P01 = D01 * F0;  // rows h0 scaled by F0, h1 by F1
      P10 = D10 * F1; P11 = D11 * F1;
      PACK_B()
    }

    if ((r & 7) == 7) {  // renorm every 8 (growth <= 2^13.7/step; 2^111 < 2^127)
      float4v m4 = __builtin_elementwise_max(__builtin_elementwise_max(P00, P01),
                                             __builtin_elementwise_max(P10, P11));
      float mx = fmaxf(fmaxf(m4[0], m4[1]), fmaxf(m4[2], m4[3]));
      mx = fmaxf(mx, __shfl_xor(mx, 1, 64));
      mx = fmaxf(mx, __shfl_xor(mx, 2, 64));
      mx = fmaxf(mx, __shfl_xor(mx, 4, 64));
      mx = fmaxf(mx, __shfl_xor(mx, 8, 64));
      mx = fmaxf(mx, __shfl_xor(mx, 16, 64));
      mx = fmaxf(mx, __shfl_xor(mx, 32, 64));
      int ex = (int)((__float_as_uint(mx) >> 23) & 0xFFu) - 127;
      float scl = __uint_as_float((unsigned)(127 - ex) << 23);  // exact 2^-ex
      P00 *= scl; P01 *= scl; P10 *= scl; P11 *= scl;
      c2 += (float)ex;
      PACK_B()
    }
  }

  // ---- epilogue: LDS transpose (reuse gshare) -> row-major bf16 S[j*32+k] ----
  float* W = (float*)Wg;
#pragma unroll
  for (int p = 0; p < 4; ++p) {
    W[(4 * q + p) * 33 + s]            = P00[p];
    W[(4 * q + p) * 33 + 16 + s]       = P01[p];
    W[(16 + 4 * q + p) * 33 + s]       = P10[p];
    W[(16 + 4 * q + p) * 33 + 16 + s]  = P11[p];
  }
  const int j = lane >> 1, half = lane & 1;
  unsigned dw[8];
#pragma unroll
  for (int w = 0; w < 8; ++w)
    dw[w] = pk_tr(W[j * 33 + half * 16 + 2 * w], W[j * 33 + half * 16 + 2 * w + 1]);
  uint4v st0 = {dw[0], dw[1], dw[2], dw[3]}, st1 = {dw[4], dw[5], dw[6], dw[7]};
  unsigned short* Sp = S + ((size_t)gw << 10) + j * 32 + half * 16;
  *(uint4v*)(Sp)     = st0;
  *(uint4v*)(Sp + 8) = st1;
  if (lane == 0) Sc2[gw] = c2;
}

// ================= K2: serial chunk combine + epilogue =================
extern "C" __global__ void __launch_bounds__(64) crf_p2(
    const unsigned short* __restrict__ S, const float* __restrict__ Sc2,
    const float* __restrict__ trans, float* __restrict__ out) {
  const int lane = threadIdx.x, j = lane & 31;
  const int b = blockIdx.x * 2 + (lane >> 5);
  float alpha = (j == 30) ? 1.f : 0.f;  // alpha0 = delta(START=30), exp2-space
  float c2 = 0.f;

  const uint4v* rp = (const uint4v*)(S + ((size_t)(b * NC) << 10) + j * 32);
  uint4v ra = rp[0], rb = rp[1], rc = rp[2], rd = rp[3];
  float pc = Sc2[b * NC];

#define ACC2(dwv, k0)                                                          \
  { unsigned d_ = (dwv);                                                       \
    acc0 = fmaf(swz<((k0) << 5)>(alpha), __uint_as_float(d_ << 16), acc0);     \
    acc1 = fmaf(swz<(((k0) + 1) << 5)>(alpha), __uint_as_float(d_ & 0xFFFF0000u), acc1); }

#pragma unroll
  for (int c = 0; c < NC; ++c) {
    uint4v ca = ra, cb = rb, cc = rc, cd = rd;
    float cpc = pc;
    if (c + 1 < NC) {
      const uint4v* np = rp + (c + 1) * 128;
      ra = np[0]; rb = np[1]; rc = np[2]; rd = np[3];
      pc = Sc2[b * NC + c + 1];
    }
    float acc0 = 0.f, acc1 = 0.f;
    ACC2(ca[0], 0)  ACC2(ca[1], 2)  ACC2(ca[2], 4)  ACC2(ca[3], 6)
    ACC2(cb[0], 8)  ACC2(cb[1], 10) ACC2(cb[2], 12) ACC2(cb[3], 14)
    ACC2(cc[0], 16) ACC2(cc[1], 18) ACC2(cc[2], 20) ACC2(cc[3], 22)
    ACC2(cd[0], 24) ACC2(cd[1], 26) ACC2(cd[2], 28) ACC2(cd[3], 30)
    float an = acc0 + acc1;
    float mx = an;
    mx = fmaxf(mx, swz<0x041f>(mx));
    mx = fmaxf(mx, swz<0x081f>(mx));
    mx = fmaxf(mx, swz<0x101f>(mx));
    mx = fmaxf(mx, swz<0x201f>(mx));
    mx = fmaxf(mx, swz<0x401f>(mx));
    int ex = (int)((__float_as_uint(mx) >> 23) & 0xFFu) - 127;
    float scl = __uint_as_float((unsigned)(127 - ex) << 23);
    alpha = an * scl;
    c2 += cpc + (float)ex;
  }

  float v = alpha * __builtin_amdgcn_exp2f(trans[31 * TAGS + j] * LOG2E);
  v += swz<0x041f>(v); v += swz<0x081f>(v); v += swz<0x101f>(v);
  v += swz<0x201f>(v); v += swz<0x401f>(v);
  float res = LN2 * (c2 + __builtin_amdgcn_logf(v));
  if (j == 0) out[b] = res;
}

extern "C" void kernel_launch(void* const* d_in, const int* in_sizes, int n_in,
                              void* d_out, int out_size, void* d_ws, size_t ws_size,
                              hipStream_t stream) {
  const float* feats = (const float*)d_in[0];
  const float* mask  = (const float*)d_in[1];
  const float* trans = (const float*)d_in[2];
  float* out = (float*)d_out;
  unsigned short* S = (unsigned short*)d_ws;                      // 16 MB
  float* Sc2 = (float*)((char*)d_ws + 16777216);                  // 32 KB
  hipLaunchKernelGGL(crf_p1, dim3(BATCH * NC / 4), dim3(256), 0, stream,
                     feats, mask, trans, S, Sc2);
  hipLaunchKernelGGL(crf_p2, dim3(BATCH / 2), dim3(64), 0, stream,
                     S, Sc2, trans, out);
}

// Round 7
// 145.747 us; speedup vs baseline: 2.0636x; 1.0741x over previous
//
#include <hip/hip_runtime.h>

// CRF forward (log-partition), SEQ=512, BATCH=1024, TAGS=32, fp32 in/out.
//
// R7 = R6 + (a) mask -> one __ballot per chunk at staging time; per-step test
// is a scalar SGPR bit-test (removes the per-step SMEM load whose lgkmcnt(0)
// drain was serializing the ds_read G-prefetch), (b) prefetch tail-guard
// removed via safe over-read into the LDS pad, (c) p2 loads all 8 chunk rows
// upfront (one vmcnt round-trip instead of 8 serial misses).
//
//  K1 crf_p1: wave per (batch b, chunk c of 64 steps).
//    Stage: lane t loads feats row (128B) + mask[t]; 32 exp2; pack bf16
//    q-block order; 4x ds_write_b128; __ballot -> 64-bit mask in SGPRs.
//    Loop: ds_read_b128 (immediate offsets, broadcast, 2-deep prefetch) +
//    4x mfma_f32_16x16x32_bf16 sigma-feedback + row-scale + renorm/8.
//  K2 crf_p2: 8 chunk matvecs per batch (swizzle broadcast) + lse epilogue.
//
// ws: S 16 MB | Sc2 32 KB.

constexpr int SEQ = 512, BATCH = 1024, TAGS = 32;
constexpr int NC = 8, L = SEQ / NC;  // 8 chunks x 64 steps

#define LOG2E 1.4426950408889634f
#define LN2   0.6931471805599453f

typedef __attribute__((ext_vector_type(8))) short short8;
typedef __attribute__((ext_vector_type(4))) float float4v;
typedef __attribute__((ext_vector_type(4))) unsigned uint4v;
union Frag8 { unsigned u[4]; short8 v; };

__device__ __forceinline__ unsigned pk_rn(float x, float y) {  // bf16 pack, x->low
  return __builtin_amdgcn_perm(__float_as_uint(y) + 0x8000u,
                               __float_as_uint(x) + 0x8000u, 0x07060302u);
}
__device__ __forceinline__ unsigned pk_tr(float x, float y) {  // trunc pack, x->low
  return __builtin_amdgcn_perm(__float_as_uint(y), __float_as_uint(x), 0x07060302u);
}
template <int PAT> __device__ __forceinline__ float swz(float v) {
  return __int_as_float(__builtin_amdgcn_ds_swizzle(__float_as_int(v), PAT));
}

// ================= K1: fused stage + per-(b,c) chunk matrix product =================
extern "C" __global__ void __launch_bounds__(256) crf_p1(
    const float* __restrict__ feats, const float* __restrict__ mask,
    const float* __restrict__ trans, unsigned short* __restrict__ S,
    float* __restrict__ Sc2) {
  // per-wave region: 1088 dwords = staging G (1024: row t at t*16) + pad for
  // over-read prefetch (rows 64-65) and the 32x33 f32 epilogue transpose.
  __shared__ unsigned gshare[4][1088];
  const int wid_u = __builtin_amdgcn_readfirstlane((int)(threadIdx.x >> 6));
  const int lane = threadIdx.x & 63;
  const int gw = blockIdx.x * 4 + wid_u;  // 0..8191 (uniform per wave)
  const int b = gw >> 3, c = gw & 7;
  const int s = lane & 15, q = lane >> 4;
  unsigned* Wg = &gshare[wid_u][0];

  // ---- stage: lane t = lane handles row t of this chunk (+ its mask bit) ----
  unsigned long long mb;
  {
    const float* fro = feats + ((size_t)(c * L + lane) * BATCH + b) * TAGS;
    float4v fa0 = *(const float4v*)(fro);
    float4v fa1 = *(const float4v*)(fro + 4);
    float4v fa2 = *(const float4v*)(fro + 8);
    float4v fa3 = *(const float4v*)(fro + 12);
    float4v fb0 = *(const float4v*)(fro + 16);
    float4v fb1 = *(const float4v*)(fro + 20);
    float4v fb2 = *(const float4v*)(fro + 24);
    float4v fb3 = *(const float4v*)(fro + 28);
    const float mv = mask[(size_t)(c * L + lane) * BATCH + b];
    mb = __ballot(mv != 0.0f);  // bit t = step t's mask
    float ea[16], eb[16];
#pragma unroll
    for (int i = 0; i < 4; ++i) {
      ea[4 * 0 + i] = __builtin_amdgcn_exp2f(fa0[i] * LOG2E);
      ea[4 * 1 + i] = __builtin_amdgcn_exp2f(fa1[i] * LOG2E);
      ea[4 * 2 + i] = __builtin_amdgcn_exp2f(fa2[i] * LOG2E);
      ea[4 * 3 + i] = __builtin_amdgcn_exp2f(fa3[i] * LOG2E);
      eb[4 * 0 + i] = __builtin_amdgcn_exp2f(fb0[i] * LOG2E);
      eb[4 * 1 + i] = __builtin_amdgcn_exp2f(fb1[i] * LOG2E);
      eb[4 * 2 + i] = __builtin_amdgcn_exp2f(fb2[i] * LOG2E);
      eb[4 * 3 + i] = __builtin_amdgcn_exp2f(fb3[i] * LOG2E);
    }
    // row layout: 4 q-blocks of 16B; block q = rows {4q..4q+3, 16+4q..16+4q+3}
#pragma unroll
    for (int qq = 0; qq < 4; ++qq) {
      uint4v dwv;
      dwv[0] = pk_rn(ea[4 * qq + 0], ea[4 * qq + 1]);
      dwv[1] = pk_rn(ea[4 * qq + 2], ea[4 * qq + 3]);
      dwv[2] = pk_rn(eb[4 * qq + 0], eb[4 * qq + 1]);
      dwv[3] = pk_rn(eb[4 * qq + 2], eb[4 * qq + 3]);
      *(uint4v*)(Wg + lane * 16 + qq * 4) = dwv;
    }
  }

  // ---- constants: sigma-permuted E fragments ----
  int sig[8];
#pragma unroll
  for (int i = 0; i < 8; ++i) sig[i] = (i < 4) ? (4 * q + i) : (16 + 4 * q + (i - 4));
  Frag8 e0, e1;
#pragma unroll
  for (int p = 0; p < 4; ++p) {
    e0.u[p] = pk_rn(__builtin_amdgcn_exp2f(trans[s * TAGS + sig[2 * p]] * LOG2E),
                    __builtin_amdgcn_exp2f(trans[s * TAGS + sig[2 * p + 1]] * LOG2E));
    e1.u[p] = pk_rn(__builtin_amdgcn_exp2f(trans[(16 + s) * TAGS + sig[2 * p]] * LOG2E),
                    __builtin_amdgcn_exp2f(trans[(16 + s) * TAGS + sig[2 * p + 1]] * LOG2E));
  }

  // P (f32, D-layout): P_hc[p] = P[h*16+4q+p, c*16+s]. Init identity.
  float4v P00 = {0,0,0,0}, P01 = {0,0,0,0}, P10 = {0,0,0,0}, P11 = {0,0,0,0};
#pragma unroll
  for (int p = 0; p < 4; ++p) {
    float one = (4 * q + p == s) ? 1.f : 0.f;
    P00[p] = one; P11[p] = one;
  }
  Frag8 B0, B1;
  float c2 = 0.f;
  const float4v zerov = {0.f, 0.f, 0.f, 0.f};

#define PACK_B()                                                        \
  { B0.u[0] = pk_tr(P00[0], P00[1]); B0.u[1] = pk_tr(P00[2], P00[3]);   \
    B0.u[2] = pk_tr(P10[0], P10[1]); B0.u[3] = pk_tr(P10[2], P10[3]);   \
    B1.u[0] = pk_tr(P01[0], P01[1]); B1.u[1] = pk_tr(P01[2], P01[3]);   \
    B1.u[2] = pk_tr(P11[0], P11[1]); B1.u[3] = pk_tr(P11[2], P11[3]); }
  PACK_B()

  // G reads: per-wave LDS, immediate offsets, 16-way broadcast across s
  const uint4v* Wq = (const uint4v*)(Wg + q * 4);  // element t*4 = row t's q-block
#define RDG(t) (Wq[(t) * 4])

  uint4v g0 = RDG(0), g1 = RDG(1);  // 2-deep prefetch (reg-named)

#pragma unroll 8
  for (int r = 0; r < L; ++r) {
    const uint4v g = (r & 1) ? g1 : g0;
    // unguarded over-read at r+2 in {64,65}: stays inside the 1088-dword pad
    { if (r & 1) g1 = RDG(r + 2); else g0 = RDG(r + 2); }

    if ((mb >> r) & 1ull) {  // scalar bit-test; mask bit = step r's mask
      float4v D00 = __builtin_amdgcn_mfma_f32_16x16x32_bf16(e0.v, B0.v, zerov, 0, 0, 0);
      float4v D01 = __builtin_amdgcn_mfma_f32_16x16x32_bf16(e0.v, B1.v, zerov, 0, 0, 0);
      float4v D10 = __builtin_amdgcn_mfma_f32_16x16x32_bf16(e1.v, B0.v, zerov, 0, 0, 0);
      float4v D11 = __builtin_amdgcn_mfma_f32_16x16x32_bf16(e1.v, B1.v, zerov, 0, 0, 0);
      float4v F0, F1;  // unpack bf16->f32: shift/mask only
      F0[0] = __uint_as_float(g[0] << 16); F0[1] = __uint_as_float(g[0] & 0xFFFF0000u);
      F0[2] = __uint_as_float(g[1] << 16); F0[3] = __uint_as_float(g[1] & 0xFFFF0000u);
      F1[0] = __uint_as_float(g[2] << 16); F1[1] = __uint_as_float(g[2] & 0xFFFF0000u);
      F1[2] = __uint_as_float(g[3] << 16); F1[3] = __uint_as_float(g[3] & 0xFFFF0000u);
      P00 = D00 * F0; P01 = D01 * F0;  // rows h0 scaled by F0, h1 by F1
      P10 = D10 * F1; P11 = D11 * F1;
      PACK_B()
    }

    if ((r & 7) == 7) {  // renorm every 8 (growth <= 2^13.7/step; 2^111 < 2^127)
      float4v m4 = __builtin_elementwise_max(__builtin_elementwise_max(P00, P01),
                                             __builtin_elementwise_max(P10, P11));
      float mx = fmaxf(fmaxf(m4[0], m4[1]), fmaxf(m4[2], m4[3]));
      mx = fmaxf(mx, __shfl_xor(mx, 1, 64));
      mx = fmaxf(mx, __shfl_xor(mx, 2, 64));
      mx = fmaxf(mx, __shfl_xor(mx, 4, 64));
      mx = fmaxf(mx, __shfl_xor(mx, 8, 64));
      mx = fmaxf(mx, __shfl_xor(mx, 16, 64));
      mx = fmaxf(mx, __shfl_xor(mx, 32, 64));
      int ex = (int)((__float_as_uint(mx) >> 23) & 0xFFu) - 127;
      float scl = __uint_as_float((unsigned)(127 - ex) << 23);  // exact 2^-ex
      P00 *= scl; P01 *= scl; P10 *= scl; P11 *= scl;
      c2 += (float)ex;
      PACK_B()
    }
  }

  // ---- epilogue: LDS transpose (reuse gshare) -> row-major bf16 S[j*32+k] ----
  float* W = (float*)Wg;
  __builtin_amdgcn_s_waitcnt(0);  // ensure loop ds_reads done before overwrite
  __builtin_amdgcn_wave_barrier();
#pragma unroll
  for (int p = 0; p < 4; ++p) {
    W[(4 * q + p) * 33 + s]            = P00[p];
    W[(4 * q + p) * 33 + 16 + s]       = P01[p];
    W[(16 + 4 * q + p) * 33 + s]       = P10[p];
    W[(16 + 4 * q + p) * 33 + 16 + s]  = P11[p];
  }
  const int j = lane >> 1, half = lane & 1;
  unsigned dw[8];
#pragma unroll
  for (int w = 0; w < 8; ++w)
    dw[w] = pk_tr(W[j * 33 + half * 16 + 2 * w], W[j * 33 + half * 16 + 2 * w + 1]);
  uint4v st0 = {dw[0], dw[1], dw[2], dw[3]}, st1 = {dw[4], dw[5], dw[6], dw[7]};
  unsigned short* Sp = S + ((size_t)gw << 10) + j * 32 + half * 16;
  *(uint4v*)(Sp)     = st0;
  *(uint4v*)(Sp + 8) = st1;
  if (lane == 0) Sc2[gw] = c2;
}

// ================= K2: serial chunk combine + epilogue =================
extern "C" __global__ void __launch_bounds__(64) crf_p2(
    const unsigned short* __restrict__ S, const float* __restrict__ Sc2,
    const float* __restrict__ trans, float* __restrict__ out) {
  const int lane = threadIdx.x, j = lane & 31;
  const int b = blockIdx.x * 2 + (lane >> 5);

  // load ALL 8 chunks' rows + scales upfront: one vmcnt round-trip
  const uint4v* rp = (const uint4v*)(S + ((size_t)(b * NC) << 10) + j * 32);
  uint4v rr[NC][4];
  float pc[NC];
#pragma unroll
  for (int c = 0; c < NC; ++c) {
#pragma unroll
    for (int w = 0; w < 4; ++w) rr[c][w] = rp[c * 128 + w];
    pc[c] = Sc2[b * NC + c];
  }

  float alpha = (j == 30) ? 1.f : 0.f;  // alpha0 = delta(START=30), exp2-space
  float c2 = 0.f;

#define ACC2(dwv, k0)                                                          \
  { unsigned d_ = (dwv);                                                       \
    acc0 = fmaf(swz<((k0) << 5)>(alpha), __uint_as_float(d_ << 16), acc0);     \
    acc1 = fmaf(swz<(((k0) + 1) << 5)>(alpha), __uint_as_float(d_ & 0xFFFF0000u), acc1); }

#pragma unroll
  for (int c = 0; c < NC; ++c) {
    float acc0 = 0.f, acc1 = 0.f;
    ACC2(rr[c][0][0], 0)  ACC2(rr[c][0][1], 2)  ACC2(rr[c][0][2], 4)  ACC2(rr[c][0][3], 6)
    ACC2(rr[c][1][0], 8)  ACC2(rr[c][1][1], 10) ACC2(rr[c][1][2], 12) ACC2(rr[c][1][3], 14)
    ACC2(rr[c][2][0], 16) ACC2(rr[c][2][1], 18) ACC2(rr[c][2][2], 20) ACC2(rr[c][2][3], 22)
    ACC2(rr[c][3][0], 24) ACC2(rr[c][3][1], 26) ACC2(rr[c][3][2], 28) ACC2(rr[c][3][3], 30)
    float an = acc0 + acc1;
    float mx = an;
    mx = fmaxf(mx, swz<0x041f>(mx));
    mx = fmaxf(mx, swz<0x081f>(mx));
    mx = fmaxf(mx, swz<0x101f>(mx));
    mx = fmaxf(mx, swz<0x201f>(mx));
    mx = fmaxf(mx, swz<0x401f>(mx));
    int ex = (int)((__float_as_uint(mx) >> 23) & 0xFFu) - 127;
    float scl = __uint_as_float((unsigned)(127 - ex) << 23);
    alpha = an * scl;
    c2 += pc[c] + (float)ex;
  }

  float v = alpha * __builtin_amdgcn_exp2f(trans[31 * TAGS + j] * LOG2E);
  v += swz<0x041f>(v); v += swz<0x081f>(v); v += swz<0x101f>(v);
  v += swz<0x201f>(v); v += swz<0x401f>(v);
  float res = LN2 * (c2 + __builtin_amdgcn_logf(v));
  if (j == 0) out[b] = res;
}

extern "C" void kernel_launch(void* const* d_in, const int* in_sizes, int n_in,
                              void* d_out, int out_size, void* d_ws, size_t ws_size,
                              hipStream_t stream) {
  const float* feats = (const float*)d_in[0];
  const float* mask  = (const float*)d_in[1];
  const float* trans = (const float*)d_in[2];
  float* out = (float*)d_out;
  unsigned short* S = (unsigned short*)d_ws;                      // 16 MB
  float* Sc2 = (float*)((char*)d_ws + 16777216);                  // 32 KB
  hipLaunchKernelGGL(crf_p1, dim3(BATCH * NC / 4), dim3(256), 0, stream,
                     feats, mask, trans, S, Sc2);
  hipLaunchKernelGGL(crf_p2, dim3(BATCH / 2), dim3(64), 0, stream,
                     S, Sc2, trans, out);
}

// Round 8
// 133.670 us; speedup vs baseline: 2.2500x; 1.0903x over previous
//
#include <hip/hip_runtime.h>

// CRF forward (log-partition), SEQ=512, BATCH=1024, TAGS=32, fp32 in/out.
//
// R8 = R7 + (a) __launch_bounds__(256,4): 128-reg budget so ALL loop state
// stays in VGPRs (R7's 44-VGPR report + 3x VALU inflation = AGPR move churn),
// (b) G stored as f32 in LDS, stride 36 dwords (16B-aligned, bank-rotated):
// no per-step unpack; 2x ds_read_b128 broadcast reads per step.
//
//  K1 crf_p1: wave per (batch b, chunk c of 64 steps).
//    Stage: lane t loads feats row (128B) + mask[t]; 32 exp2 (f32);
//    8x ds_write_b128 at t*36; __ballot -> 64-bit mask in SGPRs.
//    Loop: 2x ds_read_b128 (immediate offsets, 2-deep prefetch) +
//    4x mfma_f32_16x16x32_bf16 sigma-feedback + pk_mul row-scale + renorm/8.
//  K2 crf_p2: per batch: load all 8 chunk rows upfront, 8 matvecs
//    (swizzle broadcast) + lse epilogue.
//
// ws: S 16 MB | Sc2 32 KB.

constexpr int SEQ = 512, BATCH = 1024, TAGS = 32;
constexpr int NC = 8, L = SEQ / NC;  // 8 chunks x 64 steps
constexpr int RSTRIDE = 36;          // LDS row stride in dwords

#define LOG2E 1.4426950408889634f
#define LN2   0.6931471805599453f

typedef __attribute__((ext_vector_type(8))) short short8;
typedef __attribute__((ext_vector_type(4))) float float4v;
typedef __attribute__((ext_vector_type(4))) unsigned uint4v;
union Frag8 { unsigned u[4]; short8 v; };

__device__ __forceinline__ unsigned pk_rn(float x, float y) {  // bf16 pack, x->low
  return __builtin_amdgcn_perm(__float_as_uint(y) + 0x8000u,
                               __float_as_uint(x) + 0x8000u, 0x07060302u);
}
__device__ __forceinline__ unsigned pk_tr(float x, float y) {  // trunc pack, x->low
  return __builtin_amdgcn_perm(__float_as_uint(y), __float_as_uint(x), 0x07060302u);
}
template <int PAT> __device__ __forceinline__ float swz(float v) {
  return __int_as_float(__builtin_amdgcn_ds_swizzle(__float_as_int(v), PAT));
}

// ================= K1: fused stage + per-(b,c) chunk matrix product =================
extern "C" __global__ void __launch_bounds__(256, 4) crf_p1(
    const float* __restrict__ feats, const float* __restrict__ mask,
    const float* __restrict__ trans, unsigned short* __restrict__ S,
    float* __restrict__ Sc2) {
  // per-wave region: 66 rows x 36 dwords = 2376 dwords (rows 64-65 = prefetch
  // over-read pad; region also reused for the 32x33 f32 epilogue transpose).
  __shared__ float gshare[4][66 * RSTRIDE];
  const int wid_u = __builtin_amdgcn_readfirstlane((int)(threadIdx.x >> 6));
  const int lane = threadIdx.x & 63;
  const int gw = blockIdx.x * 4 + wid_u;  // 0..8191 (uniform per wave)
  const int b = gw >> 3, c = gw & 7;
  const int s = lane & 15, q = lane >> 4;
  float* Wf = &gshare[wid_u][0];

  // ---- stage: lane t handles row t of this chunk (+ its mask bit) ----
  unsigned long long mb;
  {
    const float* fro = feats + ((size_t)(c * L + lane) * BATCH + b) * TAGS;
    float4v fv[8];
#pragma unroll
    for (int i = 0; i < 8; ++i) fv[i] = *(const float4v*)(fro + 4 * i);
    const float mv = mask[(size_t)(c * L + lane) * BATCH + b];
    mb = __ballot(mv != 0.0f);  // bit t = step t's mask
#pragma unroll
    for (int i = 0; i < 8; ++i) {
      float4v ev;
      ev[0] = __builtin_amdgcn_exp2f(fv[i][0] * LOG2E);
      ev[1] = __builtin_amdgcn_exp2f(fv[i][1] * LOG2E);
      ev[2] = __builtin_amdgcn_exp2f(fv[i][2] * LOG2E);
      ev[3] = __builtin_amdgcn_exp2f(fv[i][3] * LOG2E);
      *(float4v*)(Wf + lane * RSTRIDE + 4 * i) = ev;  // tags 4i..4i+3, f32
    }
  }

  // ---- constants: sigma-permuted E fragments ----
  int sig[8];
#pragma unroll
  for (int i = 0; i < 8; ++i) sig[i] = (i < 4) ? (4 * q + i) : (16 + 4 * q + (i - 4));
  Frag8 e0, e1;
#pragma unroll
  for (int p = 0; p < 4; ++p) {
    e0.u[p] = pk_rn(__builtin_amdgcn_exp2f(trans[s * TAGS + sig[2 * p]] * LOG2E),
                    __builtin_amdgcn_exp2f(trans[s * TAGS + sig[2 * p + 1]] * LOG2E));
    e1.u[p] = pk_rn(__builtin_amdgcn_exp2f(trans[(16 + s) * TAGS + sig[2 * p]] * LOG2E),
                    __builtin_amdgcn_exp2f(trans[(16 + s) * TAGS + sig[2 * p + 1]] * LOG2E));
  }

  // P (f32, D-layout): P_hc[p] = P[h*16+4q+p, c*16+s]. Init identity.
  float4v P00 = {0,0,0,0}, P01 = {0,0,0,0}, P10 = {0,0,0,0}, P11 = {0,0,0,0};
#pragma unroll
  for (int p = 0; p < 4; ++p) {
    float one = (4 * q + p == s) ? 1.f : 0.f;
    P00[p] = one; P11[p] = one;
  }
  Frag8 B0, B1;
  float c2 = 0.f;
  const float4v zerov = {0.f, 0.f, 0.f, 0.f};

#define PACK_B()                                                        \
  { B0.u[0] = pk_tr(P00[0], P00[1]); B0.u[1] = pk_tr(P00[2], P00[3]);   \
    B0.u[2] = pk_tr(P10[0], P10[1]); B0.u[3] = pk_tr(P10[2], P10[3]);   \
    B1.u[0] = pk_tr(P01[0], P01[1]); B1.u[1] = pk_tr(P01[2], P01[3]);   \
    B1.u[2] = pk_tr(P11[0], P11[1]); B1.u[3] = pk_tr(P11[2], P11[3]); }
  PACK_B()

  // G reads: F0 = G[r, 4q..4q+3] at r*36+q*4; F1 = G[r, 16+4q..] at +16.
  // 16-way broadcast across s, 4 distinct 16B addrs per half: conflict-free.
#define RDF0(t) (*(const float4v*)(Wf + (t) * RSTRIDE + q * 4))
#define RDF1(t) (*(const float4v*)(Wf + (t) * RSTRIDE + 16 + q * 4))

  float4v F0a = RDF0(0), F1a = RDF1(0), F0b = RDF0(1), F1b = RDF1(1);

#pragma unroll 8
  for (int r = 0; r < L; ++r) {
    const float4v F0 = (r & 1) ? F0b : F0a;
    const float4v F1 = (r & 1) ? F1b : F1a;
    // unguarded over-read at r+2 in {64,65}: stays inside the 66-row pad
    if (r & 1) { F0b = RDF0(r + 2); F1b = RDF1(r + 2); }
    else       { F0a = RDF0(r + 2); F1a = RDF1(r + 2); }

    if ((mb >> r) & 1ull) {  // scalar bit-test
      float4v D00 = __builtin_amdgcn_mfma_f32_16x16x32_bf16(e0.v, B0.v, zerov, 0, 0, 0);
      float4v D01 = __builtin_amdgcn_mfma_f32_16x16x32_bf16(e0.v, B1.v, zerov, 0, 0, 0);
      float4v D10 = __builtin_amdgcn_mfma_f32_16x16x32_bf16(e1.v, B0.v, zerov, 0, 0, 0);
      float4v D11 = __builtin_amdgcn_mfma_f32_16x16x32_bf16(e1.v, B1.v, zerov, 0, 0, 0);
      P00 = D00 * F0; P01 = D01 * F0;  // rows h0 scaled by F0, h1 by F1 (pk_mul)
      P10 = D10 * F1; P11 = D11 * F1;
      PACK_B()
    }

    if ((r & 7) == 7) {  // renorm every 8 (growth <= 2^13.7/step; 2^111 < 2^127)
      float4v m4 = __builtin_elementwise_max(__builtin_elementwise_max(P00, P01),
                                             __builtin_elementwise_max(P10, P11));
      float mx = fmaxf(fmaxf(m4[0], m4[1]), fmaxf(m4[2], m4[3]));
      mx = fmaxf(mx, __shfl_xor(mx, 1, 64));
      mx = fmaxf(mx, __shfl_xor(mx, 2, 64));
      mx = fmaxf(mx, __shfl_xor(mx, 4, 64));
      mx = fmaxf(mx, __shfl_xor(mx, 8, 64));
      mx = fmaxf(mx, __shfl_xor(mx, 16, 64));
      mx = fmaxf(mx, __shfl_xor(mx, 32, 64));
      int ex = (int)((__float_as_uint(mx) >> 23) & 0xFFu) - 127;
      float scl = __uint_as_float((unsigned)(127 - ex) << 23);  // exact 2^-ex
      P00 *= scl; P01 *= scl; P10 *= scl; P11 *= scl;
      c2 += (float)ex;
      PACK_B()
    }
  }

  // ---- epilogue: LDS transpose (reuse gshare) -> row-major bf16 S[j*32+k] ----
  __builtin_amdgcn_s_waitcnt(0);  // loop ds_reads done before region reuse
  __builtin_amdgcn_wave_barrier();
#pragma unroll
  for (int p = 0; p < 4; ++p) {
    Wf[(4 * q + p) * 33 + s]            = P00[p];
    Wf[(4 * q + p) * 33 + 16 + s]       = P01[p];
    Wf[(16 + 4 * q + p) * 33 + s]       = P10[p];
    Wf[(16 + 4 * q + p) * 33 + 16 + s]  = P11[p];
  }
  const int j = lane >> 1, half = lane & 1;
  unsigned dw[8];
#pragma unroll
  for (int w = 0; w < 8; ++w)
    dw[w] = pk_tr(Wf[j * 33 + half * 16 + 2 * w], Wf[j * 33 + half * 16 + 2 * w + 1]);
  uint4v st0 = {dw[0], dw[1], dw[2], dw[3]}, st1 = {dw[4], dw[5], dw[6], dw[7]};
  unsigned short* Sp = S + ((size_t)gw << 10) + j * 32 + half * 16;
  *(uint4v*)(Sp)     = st0;
  *(uint4v*)(Sp + 8) = st1;
  if (lane == 0) Sc2[gw] = c2;
}

// ================= K2: serial chunk combine + epilogue =================
extern "C" __global__ void __launch_bounds__(64) crf_p2(
    const unsigned short* __restrict__ S, const float* __restrict__ Sc2,
    const float* __restrict__ trans, float* __restrict__ out) {
  const int lane = threadIdx.x, j = lane & 31;
  const int b = blockIdx.x * 2 + (lane >> 5);

  // load ALL 8 chunks' rows + scales upfront: one vmcnt round-trip
  const uint4v* rp = (const uint4v*)(S + ((size_t)(b * NC) << 10) + j * 32);
  uint4v rr[NC][4];
  float pc[NC];
#pragma unroll
  for (int c = 0; c < NC; ++c) {
#pragma unroll
    for (int w = 0; w < 4; ++w) rr[c][w] = rp[c * 128 + w];
    pc[c] = Sc2[b * NC + c];
  }

  float alpha = (j == 30) ? 1.f : 0.f;  // alpha0 = delta(START=30), exp2-space
  float c2 = 0.f;

#define ACC2(dwv, k0)                                                          \
  { unsigned d_ = (dwv);                                                       \
    acc0 = fmaf(swz<((k0) << 5)>(alpha), __uint_as_float(d_ << 16), acc0);     \
    acc1 = fmaf(swz<(((k0) + 1) << 5)>(alpha), __uint_as_float(d_ & 0xFFFF0000u), acc1); }

#pragma unroll
  for (int c = 0; c < NC; ++c) {
    float acc0 = 0.f, acc1 = 0.f;
    ACC2(rr[c][0][0], 0)  ACC2(rr[c][0][1], 2)  ACC2(rr[c][0][2], 4)  ACC2(rr[c][0][3], 6)
    ACC2(rr[c][1][0], 8)  ACC2(rr[c][1][1], 10) ACC2(rr[c][1][2], 12) ACC2(rr[c][1][3], 14)
    ACC2(rr[c][2][0], 16) ACC2(rr[c][2][1], 18) ACC2(rr[c][2][2], 20) ACC2(rr[c][2][3], 22)
    ACC2(rr[c][3][0], 24) ACC2(rr[c][3][1], 26) ACC2(rr[c][3][2], 28) ACC2(rr[c][3][3], 30)
    float an = acc0 + acc1;
    float mx = an;
    mx = fmaxf(mx, swz<0x041f>(mx));
    mx = fmaxf(mx, swz<0x081f>(mx));
    mx = fmaxf(mx, swz<0x101f>(mx));
    mx = fmaxf(mx, swz<0x201f>(mx));
    mx = fmaxf(mx, swz<0x401f>(mx));
    int ex = (int)((__float_as_uint(mx) >> 23) & 0xFFu) - 127;
    float scl = __uint_as_float((unsigned)(127 - ex) << 23);
    alpha = an * scl;
    c2 += pc[c] + (float)ex;
  }

  float v = alpha * __builtin_amdgcn_exp2f(trans[31 * TAGS + j] * LOG2E);
  v += swz<0x041f>(v); v += swz<0x081f>(v); v += swz<0x101f>(v);
  v += swz<0x201f>(v); v += swz<0x401f>(v);
  float res = LN2 * (c2 + __builtin_amdgcn_logf(v));
  if (j == 0) out[b] = res;
}

extern "C" void kernel_launch(void* const* d_in, const int* in_sizes, int n_in,
                              void* d_out, int out_size, void* d_ws, size_t ws_size,
                              hipStream_t stream) {
  const float* feats = (const float*)d_in[0];
  const float* mask  = (const float*)d_in[1];
  const float* trans = (const float*)d_in[2];
  float* out = (float*)d_out;
  unsigned short* S = (unsigned short*)d_ws;                      // 16 MB
  float* Sc2 = (float*)((char*)d_ws + 16777216);                  // 32 KB
  hipLaunchKernelGGL(crf_p1, dim3(BATCH * NC / 4), dim3(256), 0, stream,
                     feats, mask, trans, S, Sc2);
  hipLaunchKernelGGL(crf_p2, dim3(BATCH / 2), dim3(64), 0, stream,
                     S, Sc2, trans, out);
}

// Round 9
// 128.240 us; speedup vs baseline: 2.3453x; 1.0423x over previous
//
#include <hip/hip_runtime.h>

// CRF forward (log-partition), SEQ=512, BATCH=1024, TAGS=32, fp32 in/out.
//
// R9: SINGLE fused kernel. Block = 512 threads = 8 waves = the 8 chunks of one
// batch (1024 blocks). Each wave: R8's chunk-product loop (64 steps, 4x
// mfma_f32_16x16x32_bf16 sigma-feedback, f32 G staged in per-wave LDS,
// ballot-mask, renorm-by-2^ex every 8). Then an in-block 3-level MFMA tree
// combines the 8 chunk matrices (M = P7...P0) via LDS — no global S, no
// second kernel, no 32 MB HBM round-trip. Epilogue: column-30 dot with
// E_end, logsumexp, out[b].

constexpr int SEQ = 512, BATCH = 1024, TAGS = 32;
constexpr int NC = 8, L = SEQ / NC;  // 8 chunks x 64 steps
constexpr int RSTRIDE = 36;          // LDS row stride in dwords

#define LOG2E 1.4426950408889634f
#define LN2   0.6931471805599453f

typedef __attribute__((ext_vector_type(8))) short short8;
typedef __attribute__((ext_vector_type(4))) float float4v;
union Frag8 { unsigned u[4]; short8 v; };

__device__ __forceinline__ unsigned pk_rn(float x, float y) {  // bf16 pack, x->low
  return __builtin_amdgcn_perm(__float_as_uint(y) + 0x8000u,
                               __float_as_uint(x) + 0x8000u, 0x07060302u);
}
__device__ __forceinline__ unsigned pk_tr(float x, float y) {  // trunc pack, x->low
  return __builtin_amdgcn_perm(__float_as_uint(y), __float_as_uint(x), 0x07060302u);
}

// 32x32 matmul D = A*B via 4 MFMAs; A,B are f32 matrices in LDS (row*RSTRIDE+col).
// Same sigma k-ordering as the main loop: slot(q,i) -> i<4 ? 4q+i : 16+4q+(i-4).
__device__ __forceinline__ void mm32(const float* __restrict__ A,
                                     const float* __restrict__ Bs,
                                     int s, int q, float4v D[4]) {
  Frag8 fa0, fa1, fb0, fb1;
  const float* ar0 = A + s * RSTRIDE;         // A rows s   -> D rows 0-15
  const float* ar1 = A + (16 + s) * RSTRIDE;  // A rows 16+s-> D rows 16-31
  fa0.u[0] = pk_rn(ar0[4 * q + 0], ar0[4 * q + 1]);
  fa0.u[1] = pk_rn(ar0[4 * q + 2], ar0[4 * q + 3]);
  fa0.u[2] = pk_rn(ar0[16 + 4 * q + 0], ar0[16 + 4 * q + 1]);
  fa0.u[3] = pk_rn(ar0[16 + 4 * q + 2], ar0[16 + 4 * q + 3]);
  fa1.u[0] = pk_rn(ar1[4 * q + 0], ar1[4 * q + 1]);
  fa1.u[1] = pk_rn(ar1[4 * q + 2], ar1[4 * q + 3]);
  fa1.u[2] = pk_rn(ar1[16 + 4 * q + 0], ar1[16 + 4 * q + 1]);
  fa1.u[3] = pk_rn(ar1[16 + 4 * q + 2], ar1[16 + 4 * q + 3]);
  fb0.u[0] = pk_rn(Bs[(4 * q + 0) * RSTRIDE + s], Bs[(4 * q + 1) * RSTRIDE + s]);
  fb0.u[1] = pk_rn(Bs[(4 * q + 2) * RSTRIDE + s], Bs[(4 * q + 3) * RSTRIDE + s]);
  fb0.u[2] = pk_rn(Bs[(16 + 4 * q + 0) * RSTRIDE + s], Bs[(16 + 4 * q + 1) * RSTRIDE + s]);
  fb0.u[3] = pk_rn(Bs[(16 + 4 * q + 2) * RSTRIDE + s], Bs[(16 + 4 * q + 3) * RSTRIDE + s]);
  fb1.u[0] = pk_rn(Bs[(4 * q + 0) * RSTRIDE + 16 + s], Bs[(4 * q + 1) * RSTRIDE + 16 + s]);
  fb1.u[1] = pk_rn(Bs[(4 * q + 2) * RSTRIDE + 16 + s], Bs[(4 * q + 3) * RSTRIDE + 16 + s]);
  fb1.u[2] = pk_rn(Bs[(16 + 4 * q + 0) * RSTRIDE + 16 + s], Bs[(16 + 4 * q + 1) * RSTRIDE + 16 + s]);
  fb1.u[3] = pk_rn(Bs[(16 + 4 * q + 2) * RSTRIDE + 16 + s], Bs[(16 + 4 * q + 3) * RSTRIDE + 16 + s]);
  const float4v z = {0.f, 0.f, 0.f, 0.f};
  D[0] = __builtin_amdgcn_mfma_f32_16x16x32_bf16(fa0.v, fb0.v, z, 0, 0, 0);
  D[1] = __builtin_amdgcn_mfma_f32_16x16x32_bf16(fa0.v, fb1.v, z, 0, 0, 0);
  D[2] = __builtin_amdgcn_mfma_f32_16x16x32_bf16(fa1.v, fb0.v, z, 0, 0, 0);
  D[3] = __builtin_amdgcn_mfma_f32_16x16x32_bf16(fa1.v, fb1.v, z, 0, 0, 0);
}

__device__ __forceinline__ void wrD(float* __restrict__ W, int s, int q,
                                    const float4v D[4]) {
#pragma unroll
  for (int p = 0; p < 4; ++p) {
    W[(4 * q + p) * RSTRIDE + s]           = D[0][p];
    W[(4 * q + p) * RSTRIDE + 16 + s]      = D[1][p];
    W[(16 + 4 * q + p) * RSTRIDE + s]      = D[2][p];
    W[(16 + 4 * q + p) * RSTRIDE + 16 + s] = D[3][p];
  }
}

extern "C" __global__ void __launch_bounds__(512, 4) crf_fused(
    const float* __restrict__ feats, const float* __restrict__ mask,
    const float* __restrict__ trans, float* __restrict__ out) {
  // per-wave region: 66 rows x 36 dwords (rows 64-65 = prefetch over-read pad;
  // reused post-loop for the 32x36 f32 P matrix).
  __shared__ float gshare[8][66 * RSTRIDE];  // 76 KB
  __shared__ float c2s[8];
  const int wid_u = __builtin_amdgcn_readfirstlane((int)(threadIdx.x >> 6));
  const int lane = threadIdx.x & 63;
  const int b = blockIdx.x;       // one batch per block
  const int c = wid_u;            // one chunk per wave
  const int s = lane & 15, q = lane >> 4;
  float* Wf = &gshare[wid_u][0];

  // ---- stage: lane t handles row t of this chunk (+ its mask bit) ----
  unsigned long long mb;
  {
    const float* fro = feats + ((size_t)(c * L + lane) * BATCH + b) * TAGS;
    float4v fv[8];
#pragma unroll
    for (int i = 0; i < 8; ++i) fv[i] = *(const float4v*)(fro + 4 * i);
    const float mv = mask[(size_t)(c * L + lane) * BATCH + b];
    mb = __ballot(mv != 0.0f);  // bit t = step t's mask
#pragma unroll
    for (int i = 0; i < 8; ++i) {
      float4v ev;
      ev[0] = __builtin_amdgcn_exp2f(fv[i][0] * LOG2E);
      ev[1] = __builtin_amdgcn_exp2f(fv[i][1] * LOG2E);
      ev[2] = __builtin_amdgcn_exp2f(fv[i][2] * LOG2E);
      ev[3] = __builtin_amdgcn_exp2f(fv[i][3] * LOG2E);
      *(float4v*)(Wf + lane * RSTRIDE + 4 * i) = ev;  // tags 4i..4i+3, f32
    }
  }

  // ---- constants: sigma-permuted E fragments ----
  int sig[8];
#pragma unroll
  for (int i = 0; i < 8; ++i) sig[i] = (i < 4) ? (4 * q + i) : (16 + 4 * q + (i - 4));
  Frag8 e0, e1;
#pragma unroll
  for (int p = 0; p < 4; ++p) {
    e0.u[p] = pk_rn(__builtin_amdgcn_exp2f(trans[s * TAGS + sig[2 * p]] * LOG2E),
                    __builtin_amdgcn_exp2f(trans[s * TAGS + sig[2 * p + 1]] * LOG2E));
    e1.u[p] = pk_rn(__builtin_amdgcn_exp2f(trans[(16 + s) * TAGS + sig[2 * p]] * LOG2E),
                    __builtin_amdgcn_exp2f(trans[(16 + s) * TAGS + sig[2 * p + 1]] * LOG2E));
  }
  // E_end weights for the final dot (rows this lane holds in D-layout)
  float ef0[4], ef1[4];
#pragma unroll
  for (int p = 0; p < 4; ++p) {
    ef0[p] = __builtin_amdgcn_exp2f(trans[31 * TAGS + (4 * q + p)] * LOG2E);
    ef1[p] = __builtin_amdgcn_exp2f(trans[31 * TAGS + (16 + 4 * q + p)] * LOG2E);
  }

  // P (f32, D-layout): P_hc[p] = P[h*16+4q+p, c*16+s]. Init identity.
  float4v P00 = {0,0,0,0}, P01 = {0,0,0,0}, P10 = {0,0,0,0}, P11 = {0,0,0,0};
#pragma unroll
  for (int p = 0; p < 4; ++p) {
    float one = (4 * q + p == s) ? 1.f : 0.f;
    P00[p] = one; P11[p] = one;
  }
  Frag8 B0, B1;
  float c2 = 0.f;
  const float4v zerov = {0.f, 0.f, 0.f, 0.f};

#define PACK_B()                                                        \
  { B0.u[0] = pk_tr(P00[0], P00[1]); B0.u[1] = pk_tr(P00[2], P00[3]);   \
    B0.u[2] = pk_tr(P10[0], P10[1]); B0.u[3] = pk_tr(P10[2], P10[3]);   \
    B1.u[0] = pk_tr(P01[0], P01[1]); B1.u[1] = pk_tr(P01[2], P01[3]);   \
    B1.u[2] = pk_tr(P11[0], P11[1]); B1.u[3] = pk_tr(P11[2], P11[3]); }
  PACK_B()

#define RDF0(t) (*(const float4v*)(Wf + (t) * RSTRIDE + q * 4))
#define RDF1(t) (*(const float4v*)(Wf + (t) * RSTRIDE + 16 + q * 4))

  float4v F0a = RDF0(0), F1a = RDF1(0), F0b = RDF0(1), F1b = RDF1(1);

#pragma unroll 8
  for (int r = 0; r < L; ++r) {
    const float4v F0 = (r & 1) ? F0b : F0a;
    const float4v F1 = (r & 1) ? F1b : F1a;
    // unguarded over-read at r+2 in {64,65}: inside the 66-row pad
    if (r & 1) { F0b = RDF0(r + 2); F1b = RDF1(r + 2); }
    else       { F0a = RDF0(r + 2); F1a = RDF1(r + 2); }

    if ((mb >> r) & 1ull) {  // scalar bit-test
      float4v D00 = __builtin_amdgcn_mfma_f32_16x16x32_bf16(e0.v, B0.v, zerov, 0, 0, 0);
      float4v D01 = __builtin_amdgcn_mfma_f32_16x16x32_bf16(e0.v, B1.v, zerov, 0, 0, 0);
      float4v D10 = __builtin_amdgcn_mfma_f32_16x16x32_bf16(e1.v, B0.v, zerov, 0, 0, 0);
      float4v D11 = __builtin_amdgcn_mfma_f32_16x16x32_bf16(e1.v, B1.v, zerov, 0, 0, 0);
      P00 = D00 * F0; P01 = D01 * F0;  // rows h0 scaled by F0, h1 by F1
      P10 = D10 * F1; P11 = D11 * F1;
      PACK_B()
    }

    if ((r & 7) == 7) {  // renorm every 8 (growth <= 2^13.7/step; 2^111 < 2^127)
      float4v m4 = __builtin_elementwise_max(__builtin_elementwise_max(P00, P01),
                                             __builtin_elementwise_max(P10, P11));
      float mx = fmaxf(fmaxf(m4[0], m4[1]), fmaxf(m4[2], m4[3]));
      mx = fmaxf(mx, __shfl_xor(mx, 1, 64));
      mx = fmaxf(mx, __shfl_xor(mx, 2, 64));
      mx = fmaxf(mx, __shfl_xor(mx, 4, 64));
      mx = fmaxf(mx, __shfl_xor(mx, 8, 64));
      mx = fmaxf(mx, __shfl_xor(mx, 16, 64));
      mx = fmaxf(mx, __shfl_xor(mx, 32, 64));
      int ex = (int)((__float_as_uint(mx) >> 23) & 0xFFu) - 127;
      float scl = __uint_as_float((unsigned)(127 - ex) << 23);  // exact 2^-ex
      P00 *= scl; P01 *= scl; P10 *= scl; P11 *= scl;
      c2 += (float)ex;
      PACK_B()
    }
  }

  // ---- write P (f32, D-layout) into own region; share c2 ----
  __builtin_amdgcn_s_waitcnt(0);  // own loop ds_reads done before region reuse
  __builtin_amdgcn_wave_barrier();
  {
    float4v Pv[4] = {P00, P01, P10, P11};
    wrD(Wf, s, q, Pv);
  }
  if (lane == 0) c2s[wid_u] = c2;
  __syncthreads();

  // ---- 3-level combine tree: M = P7*P6*...*P0 ----
  float4v Dm[4];
  if (wid_u < 4) {  // Q_w = P(2w+1) * P(2w)  -> region 2w
    mm32(&gshare[2 * wid_u + 1][0], &gshare[2 * wid_u][0], s, q, Dm);
    wrD(&gshare[2 * wid_u][0], s, q, Dm);
  }
  __syncthreads();
  if (wid_u < 2) {  // R_w = Q(2w+1) * Q(2w)  -> region 4w
    mm32(&gshare[4 * wid_u + 2][0], &gshare[4 * wid_u][0], s, q, Dm);
    wrD(&gshare[4 * wid_u][0], s, q, Dm);
  }
  __syncthreads();
  if (wid_u == 0) {  // M = R1 * R0 (registers only)
    mm32(&gshare[4][0], &gshare[0][0], s, q, Dm);
    // out[b] = ln2 * (sum c2 + log2( sum_j Eend[j] * M[j][30] ))
    // col 30 = 16 + s with s == 14: Dm[1][p] = M[4q+p][16+s], Dm[3][p] = M[16+4q+p][16+s]
    float vv = 0.f;
#pragma unroll
    for (int p = 0; p < 4; ++p) vv += ef0[p] * Dm[1][p] + ef1[p] * Dm[3][p];
    vv += __shfl_xor(vv, 16, 64);
    vv += __shfl_xor(vv, 32, 64);  // now vv(s) = sum_j Eend[j]*M[j][16+s] on all q
    float c2t = ((c2s[0] + c2s[1]) + (c2s[2] + c2s[3])) +
                ((c2s[4] + c2s[5]) + (c2s[6] + c2s[7]));
    if (lane == 14) out[b] = LN2 * (c2t + __builtin_amdgcn_logf(vv));
  }
}

extern "C" void kernel_launch(void* const* d_in, const int* in_sizes, int n_in,
                              void* d_out, int out_size, void* d_ws, size_t ws_size,
                              hipStream_t stream) {
  const float* feats = (const float*)d_in[0];
  const float* mask  = (const float*)d_in[1];
  const float* trans = (const float*)d_in[2];
  float* out = (float*)d_out;
  hipLaunchKernelGGL(crf_fused, dim3(BATCH), dim3(512), 0, stream,
                     feats, mask, trans, out);
}